// Round 1
// baseline (4146.382 us; speedup 1.0000x reference)
//
#include <hip/hip_runtime.h>
#include <hip/hip_bf16.h>
#include <math.h>

// ---------- helpers ----------
__device__ __forceinline__ float elu_f(float v) {
    return v > 0.f ? v : expm1f(v);
}
__device__ __forceinline__ float sigmoid_f(float v) {
    return 1.f / (1.f + expf(-v));
}

// ---------- ConvTranspose2d(k=3, s=2, p=1, op=1) + ELU ----------
// x: [8][IC][H][W], wt: [IC][OC][3][3], out: [8][OC][2H][2W]
// Each thread owns one input pixel (i,j) -> the 2x2 output quad
// (2i,2j),(2i,2j+1),(2i+1,2j),(2i+1,2j+1). Exactly 9 FMA per ic.
template<int IC, int OC, int H, int W>
__launch_bounds__(256)
__global__ void convt_elu_k(const float* __restrict__ x, const float* __restrict__ wt,
                            const float* __restrict__ bt, float* __restrict__ out) {
    const int zz = blockIdx.z;
    const int n = zz / OC, oc = zz - n * OC;           // wave-uniform
    const int idx = blockIdx.x * 256 + threadIdx.x;    // over H*W (exact multiple)
    const int i = idx / W, j = idx - i * W;

    const float* xb = x + ((size_t)n * IC) * (H * W) + idx;
    const float bias = bt[oc];
    float a00 = bias, a01 = bias, a10 = bias, a11 = bias;

    const bool jp = (j + 1 < W), ip = (i + 1 < H);
    // branchless neighbor loads: clamp offset (always in-bounds) then mask
    const int  o01 = jp ? 1 : 0;
    const int  o10 = ip ? W : 0;
    const int  o11 = (ip && jp) ? (W + 1) : 0;
    const float m01 = jp ? 1.f : 0.f;
    const float m10 = ip ? 1.f : 0.f;
    const float m11 = (ip && jp) ? 1.f : 0.f;

    const float* wkb = wt + (size_t)oc * 9;            // + ic*OC*9 each iter (uniform)

    for (int ic = 0; ic < IC; ++ic) {
        const float* xp = xb + (size_t)ic * (H * W);
        const float x00 = xp[0];
        const float x01 = xp[o01] * m01;
        const float x10 = xp[o10] * m10;
        const float x11 = xp[o11] * m11;
        const float* wk = wkb + (size_t)ic * (OC * 9); // uniform address -> s_load
        a00 = fmaf(x00, wk[4], a00);
        a01 = fmaf(x00, wk[5], fmaf(x01, wk[3], a01));
        a10 = fmaf(x00, wk[7], fmaf(x10, wk[1], a10));
        a11 = fmaf(x00, wk[8], fmaf(x01, wk[6], fmaf(x10, wk[2], fmaf(x11, wk[0], a11))));
    }
    const int OW = 2 * W;
    float* ob = out + (((size_t)n * OC + oc) * (2 * H) + 2 * i) * OW + 2 * j;
    ob[0]      = elu_f(a00);
    ob[1]      = elu_f(a01);
    ob[OW]     = elu_f(a10);
    ob[OW + 1] = elu_f(a11);
}

// ---------- Conv2d(k=3, pad=1) + ELU ----------
// x: [8][C][H][W], wc: [C][C][3][3], out: [8][C][H][W]
// Each thread computes 4 consecutive outputs along w (float4 row loads).
template<int C, int H, int W>
__launch_bounds__(256)
__global__ void conv3_elu_k(const float* __restrict__ x, const float* __restrict__ wc,
                            const float* __restrict__ bc, float* __restrict__ out) {
    const int zz = blockIdx.z;
    const int n = zz / C, oc = zz - n * C;             // wave-uniform
    const int pix0 = blockIdx.x * 1024 + threadIdx.x * 4;
    const int h = pix0 / W, w0 = pix0 - h * W;         // w0 % 4 == 0

    const float* xb = x + ((size_t)n * C) * (H * W) + (size_t)h * W + w0;
    const float bias = bc[oc];
    float a0 = bias, a1 = bias, a2 = bias, a3 = bias;

    const bool hm = h > 0, hp = h + 1 < H;
    const bool wm = w0 > 0, wp = w0 + 4 < W;
    const int  oml = wm ? -1 : 0;  const float fml = wm ? 1.f : 0.f;
    const int  opr = wp ?  4 : 0;  const float fpr = wp ? 1.f : 0.f;

    const float* wkb = wc + (size_t)oc * C * 9;        // uniform

    for (int ic = 0; ic < C; ++ic) {
        const float* xp = xb + (size_t)ic * (H * W);
        const float* wk = wkb + (size_t)ic * 9;        // uniform -> s_load
        float rr[3][6];
        #pragma unroll
        for (int kh = 0; kh < 3; ++kh) {
            const bool rv = (kh == 1) || (kh == 0 ? hm : hp);
            if (rv) {
                const float* rp = xp + (kh - 1) * W;
                const float4 mid = *(const float4*)rp;
                rr[kh][0] = rp[oml] * fml;
                rr[kh][1] = mid.x; rr[kh][2] = mid.y; rr[kh][3] = mid.z; rr[kh][4] = mid.w;
                rr[kh][5] = rp[opr] * fpr;
            } else {
                rr[kh][0] = rr[kh][1] = rr[kh][2] = rr[kh][3] = rr[kh][4] = rr[kh][5] = 0.f;
            }
        }
        #pragma unroll
        for (int kh = 0; kh < 3; ++kh) {
            const float wa = wk[kh * 3 + 0], wb = wk[kh * 3 + 1], wcc = wk[kh * 3 + 2];
            a0 = fmaf(rr[kh][0], wa, fmaf(rr[kh][1], wb, fmaf(rr[kh][2], wcc, a0)));
            a1 = fmaf(rr[kh][1], wa, fmaf(rr[kh][2], wb, fmaf(rr[kh][3], wcc, a1)));
            a2 = fmaf(rr[kh][2], wa, fmaf(rr[kh][3], wb, fmaf(rr[kh][4], wcc, a2)));
            a3 = fmaf(rr[kh][3], wa, fmaf(rr[kh][4], wb, fmaf(rr[kh][5], wcc, a3)));
        }
    }
    float4 o;
    o.x = elu_f(a0); o.y = elu_f(a1); o.z = elu_f(a2); o.w = elu_f(a3);
    *(float4*)(out + ((size_t)n * C + oc) * (H * W) + (size_t)h * W + w0) = o;
}

// ---------- 1x1 conv 32->16 (q and kf) ----------
// x: [8][32][N], out: [8][16][N]
__launch_bounds__(256)
__global__ void conv1x1_k(const float* __restrict__ x, const float* __restrict__ wa,
                          const float* __restrict__ ba, float* __restrict__ out) {
    const int b = blockIdx.y;
    const int nn = blockIdx.x * 256 + threadIdx.x;
    const size_t N = 65536;
    const float* xb = x + (size_t)b * 32 * N + nn;
    float xv[32];
    #pragma unroll
    for (int e = 0; e < 32; ++e) xv[e] = xb[(size_t)e * N];
    float* ob = out + (size_t)b * 16 * N + nn;
    #pragma unroll
    for (int c = 0; c < 16; ++c) {
        float acc = ba[c];
        #pragma unroll
        for (int e = 0; e < 32; ++e) acc = fmaf(wa[c * 32 + e], xv[e], acc);
        ob[(size_t)c * N] = acc;
    }
}

// ---------- attention Gram partials: part[b][chunk][c*16+d] ----------
__launch_bounds__(256)
__global__ void attn_partial_k(const float* __restrict__ q, const float* __restrict__ kf,
                               float* __restrict__ part) {
    const int b = blockIdx.y;
    const int chunk = blockIdx.x;                  // 32 chunks of 2048
    const int tid = threadIdx.x;
    const int c = tid >> 4, d = tid & 15;
    __shared__ float qs[16][260];
    __shared__ float ks[16][260];
    const size_t N = 65536;
    const float* qb = q  + (size_t)b * 16 * N + (size_t)chunk * 2048;
    const float* kb = kf + (size_t)b * 16 * N + (size_t)chunk * 2048;
    float acc = 0.f;
    for (int sub = 0; sub < 8; ++sub) {
        __syncthreads();
        #pragma unroll
        for (int t = tid; t < 4096; t += 256) {
            const int r = t >> 8, col = t & 255;
            qs[r][col] = qb[(size_t)r * N + sub * 256 + col];
            ks[r][col] = kb[(size_t)r * N + sub * 256 + col];
        }
        __syncthreads();
        const float4* qr = (const float4*)&qs[c][0];
        const float4* kr = (const float4*)&ks[d][0];
        #pragma unroll 8
        for (int j5 = 0; j5 < 64; ++j5) {
            const float4 a = qr[j5], e = kr[j5];
            acc = fmaf(a.x, e.x, acc);
            acc = fmaf(a.y, e.y, acc);
            acc = fmaf(a.z, e.z, acc);
            acc = fmaf(a.w, e.w, acc);
        }
    }
    part[((size_t)b * 32 + chunk) * 256 + tid] = acc;
}

// ---------- reduce + softmax + fold attention into u[b][e], cb[b] ----------
// out[b,n] = sigmoid(cb[b] + sum_e u[b][e] * x3[b,e,n])
__launch_bounds__(256)
__global__ void attn_finish_k(const float* __restrict__ part, const float* __restrict__ wa,
                              const float* __restrict__ ba, const float* __restrict__ wf,
                              const float* __restrict__ bf, float* __restrict__ u,
                              float* __restrict__ cb) {
    __shared__ float att[8][16][16];
    __shared__ float v[8][16];
    const int tid = threadIdx.x;
    for (int t = tid; t < 2048; t += 256) {
        const int b = t >> 8, cd = t & 255;
        float s = 0.f;
        for (int ch = 0; ch < 32; ++ch) s += part[((size_t)b * 32 + ch) * 256 + cd];
        att[b][cd >> 4][cd & 15] = s;
    }
    __syncthreads();
    if (tid < 128) {   // softmax over d for each (b,c)
        const int b = tid >> 4, c = tid & 15;
        float m = att[b][c][0];
        #pragma unroll
        for (int d = 1; d < 16; ++d) m = fmaxf(m, att[b][c][d]);
        float s = 0.f;
        #pragma unroll
        for (int d = 0; d < 16; ++d) { const float e = expf(att[b][c][d] - m); att[b][c][d] = e; s += e; }
        const float inv = 1.f / s;
        #pragma unroll
        for (int d = 0; d < 16; ++d) att[b][c][d] *= inv;
    }
    __syncthreads();
    if (tid < 128) {   // v[b][d] = wf[d] + sum_c wf[c]*att[b][c][d]
        const int b = tid >> 4, d = tid & 15;
        float s = wf[d];
        #pragma unroll
        for (int c = 0; c < 16; ++c) s = fmaf(wf[c], att[b][c][d], s);
        v[b][d] = s;
    }
    __syncthreads();
    {
        const int b = tid >> 5, e = tid & 31;   // 8*32 = 256 threads
        float s = 0.f;
        #pragma unroll
        for (int d = 0; d < 16; ++d) s = fmaf(v[b][d], wa[d * 32 + e], s);
        u[b * 32 + e] = s;
        if (e == 0) {
            float s2 = bf[0];
            #pragma unroll
            for (int d = 0; d < 16; ++d) s2 = fmaf(v[b][d], ba[d], s2);
            cb[b] = s2;
        }
    }
}

// ---------- final: out[b][n] = sigmoid(cb[b] + sum_e u[b][e]*x3[b][e][n]) ----------
__launch_bounds__(256)
__global__ void final_k(const float* __restrict__ x3, const float* __restrict__ u,
                        const float* __restrict__ cb, float* __restrict__ out) {
    const int b = blockIdx.y;
    const int nn = blockIdx.x * 256 + threadIdx.x;
    const size_t N = 65536;
    const float* xb = x3 + (size_t)b * 32 * N + nn;
    float acc = cb[b];
    #pragma unroll
    for (int e = 0; e < 32; ++e) acc = fmaf(u[b * 32 + e], xb[(size_t)e * N], acc);
    out[(size_t)b * N + nn] = sigmoid_f(acc);
}

extern "C" void kernel_launch(void* const* d_in, const int* in_sizes, int n_in,
                              void* d_out, int out_size, void* d_ws, size_t ws_size,
                              hipStream_t stream) {
    const float* enc   = (const float*)d_in[0];
    const float* sem   = (const float*)d_in[1];
    const float* wt0   = (const float*)d_in[2];
    const float* bt0   = (const float*)d_in[3];
    const float* wc0   = (const float*)d_in[4];
    const float* bc0   = (const float*)d_in[5];
    const float* wt1   = (const float*)d_in[6];
    const float* bt1   = (const float*)d_in[7];
    const float* wc1   = (const float*)d_in[8];
    const float* bc1   = (const float*)d_in[9];
    const float* wt2   = (const float*)d_in[10];
    const float* bt2   = (const float*)d_in[11];
    const float* wc2   = (const float*)d_in[12];
    const float* bc2   = (const float*)d_in[13];
    const float* wt3   = (const float*)d_in[14];
    const float* bt3   = (const float*)d_in[15];
    const float* wc3   = (const float*)d_in[16];
    const float* bc3   = (const float*)d_in[17];
    const float* wattn = (const float*)d_in[18];
    const float* battn = (const float*)d_in[19];
    const float* wfin  = (const float*)d_in[20];
    const float* bfin  = (const float*)d_in[21];

    float* ws   = (float*)d_ws;
    float* buf1 = ws;                       // 16,777,216 floats (64 MB)
    float* buf2 = ws + 16777216;            // 16,777,216 floats (64 MB)
    float* part = ws + 33554432;            // 65,536 floats
    float* u    = part + 65536;             // 256 floats
    float* cb   = u + 256;                  // 8 floats
    float* kf   = buf1;                     // reuse buf1 after decoder (32 MB)
    float* q    = buf1 + 8388608;           // (32 MB)
    float* out  = (float*)d_out;

    // decoder: 4x (convT + ELU -> conv3x3 + ELU), ping-pong buf1/buf2
    convt_elu_k<512, 256,  16,  16><<<dim3(1,  1, 2048), 256, 0, stream>>>(enc,  wt0, bt0, buf1);
    conv3_elu_k<256,  32,  32>     <<<dim3(1,  1, 2048), 256, 0, stream>>>(buf1, wc0, bc0, buf2);
    convt_elu_k<256, 128,  32,  32><<<dim3(4,  1, 1024), 256, 0, stream>>>(buf2, wt1, bt1, buf1);
    conv3_elu_k<128,  64,  64>     <<<dim3(4,  1, 1024), 256, 0, stream>>>(buf1, wc1, bc1, buf2);
    convt_elu_k<128,  64,  64,  64><<<dim3(16, 1,  512), 256, 0, stream>>>(buf2, wt2, bt2, buf1);
    conv3_elu_k< 64, 128, 128>     <<<dim3(16, 1,  512), 256, 0, stream>>>(buf1, wc2, bc2, buf2);
    convt_elu_k< 64,  32, 128, 128><<<dim3(64, 1,  256), 256, 0, stream>>>(buf2, wt3, bt3, buf1);
    conv3_elu_k< 32, 256, 256>     <<<dim3(64, 1,  256), 256, 0, stream>>>(buf1, wc3, bc3, buf2);
    // buf2 = x3 [8][32][256][256]; buf1 now free -> holds kf and q

    conv1x1_k<<<dim3(256, 8), 256, 0, stream>>>(buf2, wattn, battn, q);   // q  from x3
    conv1x1_k<<<dim3(256, 8), 256, 0, stream>>>(sem,  wattn, battn, kf);  // kf from semantic_map
    attn_partial_k<<<dim3(32, 8), 256, 0, stream>>>(q, kf, part);
    attn_finish_k<<<1, 256, 0, stream>>>(part, wattn, battn, wfin, bfin, u, cb);
    final_k<<<dim3(256, 8), 256, 0, stream>>>(buf2, u, cb, out);
}

// Round 2
// 1636.193 us; speedup vs baseline: 2.5342x; 2.5342x over previous
//
#include <hip/hip_runtime.h>
#include <hip/hip_bf16.h>
#include <math.h>

__device__ __forceinline__ float elu_f(float v) { return v > 0.f ? v : expm1f(v); }
__device__ __forceinline__ float sigmoid_f(float v) { return 1.f / (1.f + expf(-v)); }

// ---------- ConvTranspose2d(k=3, s=2, p=1, op=1) + ELU, v2 ----------
// x: [8][IC][H][W], wt: [IC][OC][3][3], out: [8][OC][2H][2W]
// Thread owns one input pixel -> 2x2 output quad, for OCB output channels.
// Weights staged in LDS per IC-chunk (layout [ic][tap][OCB] -> b128 broadcast reads).
template<int IC, int OC, int H, int W, int OCB, int ICB>
__launch_bounds__(256)
__global__ void convt_elu_v2(const float* __restrict__ x, const float* __restrict__ wt,
                             const float* __restrict__ bt, float* __restrict__ out) {
    const int zz = blockIdx.z;                         // 8 * (OC/OCB)
    const int n = zz / (OC / OCB), ocg = zz - n * (OC / OCB);
    const int oc0 = ocg * OCB;
    const int idx = blockIdx.x * 256 + threadIdx.x;    // over H*W
    const int i = idx / W, j = idx - i * W;

    __shared__ float wlds[ICB][9][OCB];

    const float* xb = x + ((size_t)n * IC) * (H * W) + idx;
    float acc[OCB][4];
    #pragma unroll
    for (int o = 0; o < OCB; ++o) {
        const float b = bt[oc0 + o];
        acc[o][0] = b; acc[o][1] = b; acc[o][2] = b; acc[o][3] = b;
    }

    const bool jp = (j + 1 < W), ip = (i + 1 < H);
    const int  o01 = jp ? 1 : 0;
    const int  o10 = ip ? W : 0;
    const int  o11 = (ip && jp) ? (W + 1) : 0;
    const float m01 = jp ? 1.f : 0.f;
    const float m10 = ip ? 1.f : 0.f;
    const float m11 = (ip && jp) ? 1.f : 0.f;

    for (int icc = 0; icc < IC; icc += ICB) {
        __syncthreads();
        for (int t = threadIdx.x; t < ICB * 9 * OCB; t += 256) {
            const int o = t % OCB;
            const int k = (t / OCB) % 9;
            const int ici = t / (9 * OCB);
            wlds[ici][k][o] = wt[((size_t)(icc + ici) * OC + oc0 + o) * 9 + k];
        }
        __syncthreads();
        for (int ici = 0; ici < ICB; ++ici) {
            const float* xp = xb + (size_t)(icc + ici) * (H * W);
            const float x00 = xp[0];
            const float x01 = xp[o01] * m01;
            const float x10 = xp[o10] * m10;
            const float x11 = xp[o11] * m11;
            #pragma unroll
            for (int o = 0; o < OCB; ++o) {
                acc[o][0] = fmaf(x00, wlds[ici][4][o], acc[o][0]);
                acc[o][1] = fmaf(x00, wlds[ici][5][o], fmaf(x01, wlds[ici][3][o], acc[o][1]));
                acc[o][2] = fmaf(x00, wlds[ici][7][o], fmaf(x10, wlds[ici][1][o], acc[o][2]));
                acc[o][3] = fmaf(x00, wlds[ici][8][o], fmaf(x01, wlds[ici][6][o],
                              fmaf(x10, wlds[ici][2][o], fmaf(x11, wlds[ici][0][o], acc[o][3]))));
            }
        }
    }
    const int OW = 2 * W;
    #pragma unroll
    for (int o = 0; o < OCB; ++o) {
        float* ob = out + (((size_t)n * OC + oc0 + o) * (2 * H) + 2 * i) * OW + 2 * j;
        ob[0]      = elu_f(acc[o][0]);
        ob[1]      = elu_f(acc[o][1]);
        ob[OW]     = elu_f(acc[o][2]);
        ob[OW + 1] = elu_f(acc[o][3]);
    }
}

// ---------- Conv2d(k=3, pad=1) + ELU, v2 ----------
// x: [8][C][H][W], wc: [C][C][3][3], out: [8][C][H][W]
// Thread computes PX consecutive outputs along w for OCB output channels.
template<int C, int H, int W, int OCB, int PX, int ICB>
__launch_bounds__(256)
__global__ void conv3_elu_v2(const float* __restrict__ x, const float* __restrict__ wc,
                             const float* __restrict__ bc, float* __restrict__ out) {
    const int zz = blockIdx.z;                          // 8 * (C/OCB)
    const int n = zz / (C / OCB), ocg = zz - n * (C / OCB);
    const int oc0 = ocg * OCB;
    const int pix0 = (blockIdx.x * 256 + threadIdx.x) * PX;
    const int h = pix0 / W, w0 = pix0 - h * W;          // w0 % PX == 0

    __shared__ float wlds[ICB][9][OCB];

    const float* xb = x + ((size_t)n * C) * (H * W) + (size_t)h * W + w0;
    float acc[OCB][PX];
    #pragma unroll
    for (int o = 0; o < OCB; ++o) {
        const float b = bc[oc0 + o];
        #pragma unroll
        for (int p = 0; p < PX; ++p) acc[o][p] = b;
    }

    const bool hm = h > 0, hp = h + 1 < H;
    const bool wm = w0 > 0, wp = w0 + PX < W;
    const int  oml = wm ? -1 : 0;  const float fml = wm ? 1.f : 0.f;
    const int  opr = wp ?  PX : 0; const float fpr = wp ? 1.f : 0.f;

    for (int icc = 0; icc < C; icc += ICB) {
        __syncthreads();
        for (int t = threadIdx.x; t < ICB * 9 * OCB; t += 256) {
            const int o = t % OCB;
            const int k = (t / OCB) % 9;
            const int ici = t / (9 * OCB);
            wlds[ici][k][o] = wc[((size_t)(oc0 + o) * C + icc + ici) * 9 + k];
        }
        __syncthreads();
        for (int ici = 0; ici < ICB; ++ici) {
            const float* xp = xb + (size_t)(icc + ici) * (H * W);
            float rr[3][PX + 2];
            #pragma unroll
            for (int kh = 0; kh < 3; ++kh) {
                const bool rv = (kh == 1) || (kh == 0 ? hm : hp);
                const float* rp = xp + (kh - 1) * W;
                if (rv) {
                    if constexpr (PX == 4) {
                        const float4 mid = *(const float4*)rp;
                        rr[kh][1] = mid.x; rr[kh][2] = mid.y; rr[kh][3] = mid.z; rr[kh][4] = mid.w;
                    } else {
                        const float2 mid = *(const float2*)rp;
                        rr[kh][1] = mid.x; rr[kh][2] = mid.y;
                    }
                    rr[kh][0]      = rp[oml] * fml;
                    rr[kh][PX + 1] = rp[opr] * fpr;
                } else {
                    #pragma unroll
                    for (int q = 0; q < PX + 2; ++q) rr[kh][q] = 0.f;
                }
            }
            #pragma unroll
            for (int kh = 0; kh < 3; ++kh) {
                #pragma unroll
                for (int kw = 0; kw < 3; ++kw) {
                    #pragma unroll
                    for (int o = 0; o < OCB; ++o) {
                        const float wv = wlds[ici][kh * 3 + kw][o];
                        #pragma unroll
                        for (int p = 0; p < PX; ++p)
                            acc[o][p] = fmaf(rr[kh][p + kw], wv, acc[o][p]);
                    }
                }
            }
        }
    }
    #pragma unroll
    for (int o = 0; o < OCB; ++o) {
        float* op = out + ((size_t)n * C + oc0 + o) * (H * W) + (size_t)h * W + w0;
        if constexpr (PX == 4) {
            float4 ov;
            ov.x = elu_f(acc[o][0]); ov.y = elu_f(acc[o][1]);
            ov.z = elu_f(acc[o][2]); ov.w = elu_f(acc[o][3]);
            *(float4*)op = ov;
        } else {
            float2 ov;
            ov.x = elu_f(acc[o][0]); ov.y = elu_f(acc[o][1]);
            *(float2*)op = ov;
        }
    }
}

// ---------- 32x32 Gram partials: G[b] += x3[b,:,n] * sem[b,:,n]^T ----------
// part[b][chunk][32*32], sums[b][chunk][64] (Sx 0..31, Ss 32..63)
__launch_bounds__(256)
__global__ void gram_partial_k(const float* __restrict__ x3, const float* __restrict__ sem,
                               float* __restrict__ part, float* __restrict__ sums) {
    const int b = blockIdx.y, chunk = blockIdx.x, tid = threadIdx.x;
    const int c0 = tid >> 4, d0 = tid & 15;            // 0..15 each
    __shared__ float xs[32][132];
    __shared__ float ss[32][132];
    const size_t N = 65536;
    const float* xb = x3  + (size_t)b * 32 * N + (size_t)chunk * 2048;
    const float* sb = sem + (size_t)b * 32 * N + (size_t)chunk * 2048;
    float a00 = 0.f, a01 = 0.f, a10 = 0.f, a11 = 0.f;
    float sxacc = 0.f, ssacc = 0.f;

    for (int sub = 0; sub < 16; ++sub) {
        __syncthreads();
        for (int t = tid; t < 2048; t += 256) {        // 2*32 rows * 32 float4
            const int arr = t >> 10, slot = t & 1023;
            const int r = slot >> 5, c4 = slot & 31;
            const float4 v = *(const float4*)((arr ? sb : xb) + (size_t)r * N + sub * 128 + c4 * 4);
            float* dst = arr ? &ss[r][c4 * 4] : &xs[r][c4 * 4];
            *(float4*)dst = v;
        }
        __syncthreads();
        #pragma unroll 8
        for (int j4 = 0; j4 < 32; ++j4) {
            const float4 xa = *(const float4*)&xs[c0][j4 * 4];
            const float4 xc = *(const float4*)&xs[c0 + 16][j4 * 4];
            const float4 sa = *(const float4*)&ss[d0][j4 * 4];
            const float4 sc = *(const float4*)&ss[d0 + 16][j4 * 4];
            a00 = fmaf(xa.x, sa.x, fmaf(xa.y, sa.y, fmaf(xa.z, sa.z, fmaf(xa.w, sa.w, a00))));
            a01 = fmaf(xa.x, sc.x, fmaf(xa.y, sc.y, fmaf(xa.z, sc.z, fmaf(xa.w, sc.w, a01))));
            a10 = fmaf(xc.x, sa.x, fmaf(xc.y, sa.y, fmaf(xc.z, sa.z, fmaf(xc.w, sa.w, a10))));
            a11 = fmaf(xc.x, sc.x, fmaf(xc.y, sc.y, fmaf(xc.z, sc.z, fmaf(xc.w, sc.w, a11))));
        }
        if (tid < 128) {                               // channel sums (for bias terms)
            const int r = (tid & 63) >> 1, half = tid & 1;
            const float* src = (tid < 64) ? &xs[r][half * 64] : &ss[r][half * 64];
            float s = 0.f;
            #pragma unroll
            for (int q = 0; q < 64; ++q) s += src[q];
            if (tid < 64) sxacc += s; else ssacc += s;
        }
    }
    float* pb = part + ((size_t)b * 32 + chunk) * 1024;
    pb[c0 * 32 + d0]              = a00;
    pb[c0 * 32 + d0 + 16]         = a01;
    pb[(c0 + 16) * 32 + d0]       = a10;
    pb[(c0 + 16) * 32 + d0 + 16]  = a11;
    if (tid < 128) {
        const int r = (tid & 63) >> 1;
        const float mine = (tid < 64) ? sxacc : ssacc;
        const float tot = mine + __shfl_xor(mine, 1);
        if ((tid & 1) == 0)
            sums[((size_t)b * 32 + chunk) * 64 + (tid < 64 ? r : 32 + r)] = tot;
    }
}

// ---------- reduce Gram -> A=softmax(Wa G Wa^T + bias terms) -> u,cb ----------
__launch_bounds__(256)
__global__ void attn_finish_v2(const float* __restrict__ part, const float* __restrict__ sums,
                               const float* __restrict__ wa, const float* __restrict__ ba,
                               const float* __restrict__ wf, const float* __restrict__ bf,
                               float* __restrict__ u, float* __restrict__ cb) {
    __shared__ float G[32][33];
    __shared__ float T[16][33];
    __shared__ float A[16][17];
    __shared__ float Sx[32], Ss[32], px[16], ps[16], v[16];
    const int tid = threadIdx.x;
    for (int b = 0; b < 8; ++b) {
        __syncthreads();
        for (int t = tid; t < 1024; t += 256) {
            float s = 0.f;
            for (int ch = 0; ch < 32; ++ch) s += part[((size_t)b * 32 + ch) * 1024 + t];
            G[t >> 5][t & 31] = s;
        }
        if (tid < 64) {
            float s = 0.f;
            for (int ch = 0; ch < 32; ++ch) s += sums[((size_t)b * 32 + ch) * 64 + tid];
            if (tid < 32) Sx[tid] = s; else Ss[tid - 32] = s;
        }
        __syncthreads();
        for (int t = tid; t < 512; t += 256) {          // T = Wa * G  (16x32)
            const int c = t >> 5, f = t & 31;
            float s = 0.f;
            #pragma unroll
            for (int e = 0; e < 32; ++e) s = fmaf(wa[c * 32 + e], G[e][f], s);
            T[c][f] = s;
        }
        if (tid < 32) {                                  // px = Wa*Sx, ps = Wa*Ss
            const int c = tid & 15;
            const float* S = (tid < 16) ? Sx : Ss;
            float s = 0.f;
            #pragma unroll
            for (int e = 0; e < 32; ++e) s = fmaf(wa[c * 32 + e], S[e], s);
            if (tid < 16) px[c] = s; else ps[c] = s;
        }
        __syncthreads();
        if (tid < 256 && tid < 256) {}
        if (tid < 256) {
            if (tid < 256 && tid < 16 * 16) {            // A[c][d]
                const int c = tid >> 4, d = tid & 15;
                float s = 0.f;
                #pragma unroll
                for (int f = 0; f < 32; ++f) s = fmaf(T[c][f], wa[d * 32 + f], s);
                s += px[c] * ba[d] + ba[c] * ps[d] + 65536.f * ba[c] * ba[d];
                A[c][d] = s;
            }
        }
        __syncthreads();
        if (tid < 16) {                                  // row softmax
            float m = A[tid][0];
            #pragma unroll
            for (int d = 1; d < 16; ++d) m = fmaxf(m, A[tid][d]);
            float s = 0.f;
            #pragma unroll
            for (int d = 0; d < 16; ++d) { const float e = expf(A[tid][d] - m); A[tid][d] = e; s += e; }
            const float inv = 1.f / s;
            #pragma unroll
            for (int d = 0; d < 16; ++d) A[tid][d] *= inv;
        }
        __syncthreads();
        if (tid < 16) {                                  // v[d] = wf[d] + sum_c wf[c]*A[c][d]
            float s = wf[tid];
            #pragma unroll
            for (int c = 0; c < 16; ++c) s = fmaf(wf[c], A[c][tid], s);
            v[tid] = s;
        }
        __syncthreads();
        if (tid < 32) {                                  // u[e] = sum_d v[d]*wa[d][e]
            float s = 0.f;
            #pragma unroll
            for (int d = 0; d < 16; ++d) s = fmaf(v[d], wa[d * 32 + tid], s);
            u[b * 32 + tid] = s;
        }
        if (tid == 0) {
            float s2 = bf[0];
            #pragma unroll
            for (int d = 0; d < 16; ++d) s2 = fmaf(v[d], ba[d], s2);
            cb[b] = s2;
        }
    }
}

// ---------- final: out[b][n] = sigmoid(cb[b] + sum_e u[b][e]*x3[b][e][n]) ----------
__launch_bounds__(256)
__global__ void final_k(const float* __restrict__ x3, const float* __restrict__ u,
                        const float* __restrict__ cb, float* __restrict__ out) {
    const int b = blockIdx.y;
    const int nn = blockIdx.x * 256 + threadIdx.x;
    const size_t N = 65536;
    const float* xb = x3 + (size_t)b * 32 * N + nn;
    float acc = cb[b];
    #pragma unroll
    for (int e = 0; e < 32; ++e) acc = fmaf(u[b * 32 + e], xb[(size_t)e * N], acc);
    out[(size_t)b * N + nn] = sigmoid_f(acc);
}

extern "C" void kernel_launch(void* const* d_in, const int* in_sizes, int n_in,
                              void* d_out, int out_size, void* d_ws, size_t ws_size,
                              hipStream_t stream) {
    const float* enc   = (const float*)d_in[0];
    const float* sem   = (const float*)d_in[1];
    const float* wt0   = (const float*)d_in[2];
    const float* bt0   = (const float*)d_in[3];
    const float* wc0   = (const float*)d_in[4];
    const float* bc0   = (const float*)d_in[5];
    const float* wt1   = (const float*)d_in[6];
    const float* bt1   = (const float*)d_in[7];
    const float* wc1   = (const float*)d_in[8];
    const float* bc1   = (const float*)d_in[9];
    const float* wt2   = (const float*)d_in[10];
    const float* bt2   = (const float*)d_in[11];
    const float* wc2   = (const float*)d_in[12];
    const float* bc2   = (const float*)d_in[13];
    const float* wt3   = (const float*)d_in[14];
    const float* bt3   = (const float*)d_in[15];
    const float* wc3   = (const float*)d_in[16];
    const float* bc3   = (const float*)d_in[17];
    const float* wattn = (const float*)d_in[18];
    const float* battn = (const float*)d_in[19];
    const float* wfin  = (const float*)d_in[20];
    const float* bfin  = (const float*)d_in[21];

    float* ws   = (float*)d_ws;
    float* buf1 = ws;                       // 16,777,216 floats (64 MB)
    float* buf2 = ws + 16777216;            // 16,777,216 floats (64 MB)
    // after the decoder, buf1 is free -> attn scratch lives there
    float* part = buf1;                     // 8*32*1024 = 262,144 floats
    float* sums = buf1 + 262144;            // 8*32*64   = 16,384 floats
    float* u    = buf1 + 262144 + 16384;    // 256
    float* cb   = u + 256;                  // 8
    float* out  = (float*)d_out;

    convt_elu_v2<512, 256, 16, 16, 2, 64><<<dim3(1, 1, 1024), 256, 0, stream>>>(enc,  wt0, bt0, buf1);
    conv3_elu_v2<256, 32, 32, 4, 2, 64>  <<<dim3(2, 1, 512),  256, 0, stream>>>(buf1, wc0, bc0, buf2);
    convt_elu_v2<256, 128, 32, 32, 4, 64><<<dim3(4, 1, 256),  256, 0, stream>>>(buf2, wt1, bt1, buf1);
    conv3_elu_v2<128, 64, 64, 4, 4, 64>  <<<dim3(4, 1, 256),  256, 0, stream>>>(buf1, wc1, bc1, buf2);
    convt_elu_v2<128, 64, 64, 64, 4, 64> <<<dim3(16, 1, 128), 256, 0, stream>>>(buf2, wt2, bt2, buf1);
    conv3_elu_v2<64, 128, 128, 4, 4, 64> <<<dim3(16, 1, 128), 256, 0, stream>>>(buf1, wc2, bc2, buf2);
    convt_elu_v2<64, 32, 128, 128, 4, 64><<<dim3(64, 1, 64),  256, 0, stream>>>(buf2, wt3, bt3, buf1);
    conv3_elu_v2<32, 256, 256, 4, 4, 32> <<<dim3(64, 1, 64),  256, 0, stream>>>(buf1, wc3, bc3, buf2);
    // buf2 = x3 [8][32][256][256]

    gram_partial_k<<<dim3(32, 8), 256, 0, stream>>>(buf2, sem, part, sums);
    attn_finish_v2<<<1, 256, 0, stream>>>(part, sums, wattn, battn, wfin, bfin, u, cb);
    final_k<<<dim3(256, 8), 256, 0, stream>>>(buf2, u, cb, out);
}

// Round 3
// 455.383 us; speedup vs baseline: 9.1053x; 3.5930x over previous
//
#include <hip/hip_runtime.h>
#include <hip/hip_bf16.h>
#include <math.h>

typedef _Float16 f16;
typedef _Float16 h8 __attribute__((ext_vector_type(8)));
typedef _Float16 h4 __attribute__((ext_vector_type(4)));
typedef float    f4 __attribute__((ext_vector_type(4)));

__device__ __forceinline__ float elu_f(float v) { return v > 0.f ? v : expm1f(v); }
__device__ __forceinline__ float sigmoid_f(float v) { return 1.f / (1.f + expf(-v)); }

// ================= weight prep: all 8 tensors -> f16 [oc][tap][ic] =================
struct PrepDesc { const float* src; unsigned dstOff; int OC; int IC; int tr; };
struct P8 { PrepDesc d[8]; };

__global__ void prep_weights_k(P8 p, f16* __restrict__ wp) {
    unsigned idx = blockIdx.x * 256u + threadIdx.x;
    for (int s = 0; s < 8; ++s) {
        const int IC = p.d[s].IC, OC = p.d[s].OC;
        const unsigned cnt = (unsigned)(OC * 9 * IC);
        if (idx < cnt) {
            const int oc = idx / (9u * IC);
            const unsigned r = idx - oc * (9u * IC);
            const int tap = r / IC, ic = r - tap * IC;
            const float v = p.d[s].tr ? p.d[s].src[((size_t)ic * OC + oc) * 9 + tap]
                                      : p.d[s].src[((size_t)oc * IC + ic) * 9 + tap];
            wp[p.d[s].dstOff + idx] = (f16)v;
            return;
        }
        idx -= cnt;
    }
}

// ================= enc transpose: [8][512][16][16] f32 -> [8][256px][512] f16 ======
__global__ void enc_transpose_k(const float* __restrict__ enc, f16* __restrict__ out) {
    __shared__ float ts[32][257];
    const int b = blockIdx.x >> 4, cg = blockIdx.x & 15;
    const int tid = threadIdx.x;
    #pragma unroll
    for (int i = 0; i < 32; ++i)
        ts[i][tid] = enc[((size_t)(b * 512 + cg * 32 + i)) * 256 + tid];
    __syncthreads();
    #pragma unroll
    for (int k = 0; k < 4; ++k) {
        h8 v;
        #pragma unroll
        for (int q = 0; q < 8; ++q) v[q] = (f16)ts[k * 8 + q][tid];
        *(h8*)(out + ((size_t)(b * 256 + tid)) * 512 + cg * 32 + k * 8) = v;
    }
}

// ================= Conv2d(k3,p1)+ELU via MFMA, channel-last f16 ====================
// in [b][H][W][C], wp [C][9][C], out [b][H][W][C] (or channel-first via CF_OUT)
template<int C, int H, int W, int HT, int WT, int NWN, bool CF_OUT>
__launch_bounds__(256, 2)
__global__ void conv3_mfma(const f16* __restrict__ in, const f16* __restrict__ wp,
                           const float* __restrict__ bias, f16* __restrict__ out,
                           f16* __restrict__ outcf) {
    constexpr int NWR = 4 / NWN;
    constexpr int RH  = HT / NWR;
    constexpr int PIXR = WT + 2;
    constexpr int ROWS = HT + 2;
    constexpr int XB = ROWS * PIXR * 80;
    __shared__ __align__(16) char lds[XB + 32 * 592];
    char* xlds = lds;
    char* wlds = lds + XB;

    const int tid = threadIdx.x;
    const int wid = tid >> 6, lane = tid & 63;
    const int ln15 = lane & 15, lg = lane >> 4;
    const int ni = wid % NWN, ri = wid / NWN;
    const int bz = blockIdx.z;
    const int bb = bz / (C / 32), ocg = bz % (C / 32);
    const int oc0 = ocg * 32;
    const int h0 = blockIdx.y * HT, w0 = blockIdx.x * WT;
    const int colb = ni * 16 + ln15;

    f4 acc[RH][2] = {};

    for (int icc = 0; icc < C; icc += 32) {
        __syncthreads();
        for (int t = tid; t < ROWS * PIXR * 4; t += 256) {
            const int g = t & 3, pix = t >> 2;
            const int rr = pix / PIXR, ww = pix - rr * PIXR;
            const int gh = h0 - 1 + rr, gw = w0 - 1 + ww;
            h8 v = {};
            if (gh >= 0 && gh < H && gw >= 0 && gw < W)
                v = *(const h8*)(in + (((size_t)bb * H + gh) * W + gw) * C + icc + g * 8);
            *(h8*)(xlds + pix * 80 + g * 16) = v;
        }
        for (int t = tid; t < 1152; t += 256) {
            const int g = t & 3, s = t >> 2;
            const int o = s / 9, tap = s - o * 9;
            h8 v = *(const h8*)(wp + ((size_t)(oc0 + o) * 9 + tap) * C + icc + g * 8);
            *(h8*)(wlds + o * 592 + tap * 64 + g * 16) = v;
        }
        __syncthreads();

        h8 af[9][2];
        #pragma unroll
        for (int tap = 0; tap < 9; ++tap)
            #pragma unroll
            for (int mt = 0; mt < 2; ++mt)
                af[tap][mt] = *(const h8*)(wlds + (mt * 16 + ln15) * 592 + tap * 64 + lg * 16);

        #pragma unroll
        for (int r = 0; r < RH; ++r) {
            const int orow = ri * RH + r;
            #pragma unroll
            for (int dh = 0; dh < 3; ++dh) {
                #pragma unroll
                for (int dw = 0; dw < 3; ++dw) {
                    const h8 bf = *(const h8*)(xlds + ((orow + dh) * PIXR + colb + dw) * 80 + lg * 16);
                    acc[r][0] = __builtin_amdgcn_mfma_f32_16x16x32_f16(af[dh * 3 + dw][0], bf, acc[r][0], 0, 0, 0);
                    acc[r][1] = __builtin_amdgcn_mfma_f32_16x16x32_f16(af[dh * 3 + dw][1], bf, acc[r][1], 0, 0, 0);
                }
            }
        }
    }

    #pragma unroll
    for (int r = 0; r < RH; ++r) {
        const int oh = h0 + ri * RH + r;
        const int ow = w0 + colb;
        #pragma unroll
        for (int mt = 0; mt < 2; ++mt) {
            const int ocl = mt * 16 + lg * 4;
            const float4 b4 = *(const float4*)(bias + oc0 + ocl);
            const f4 v = acc[r][mt];
            const float e0 = elu_f(v.x + b4.x), e1 = elu_f(v.y + b4.y);
            const float e2 = elu_f(v.z + b4.z), e3 = elu_f(v.w + b4.w);
            if constexpr (CF_OUT) {
                const size_t n = (size_t)oh * W + ow;
                const size_t plane = (size_t)H * W;
                outcf[((size_t)bb * C + oc0 + ocl + 0) * plane + n] = (f16)e0;
                outcf[((size_t)bb * C + oc0 + ocl + 1) * plane + n] = (f16)e1;
                outcf[((size_t)bb * C + oc0 + ocl + 2) * plane + n] = (f16)e2;
                outcf[((size_t)bb * C + oc0 + ocl + 3) * plane + n] = (f16)e3;
            } else {
                h4 hv = {(f16)e0, (f16)e1, (f16)e2, (f16)e3};
                *(h4*)(out + (((size_t)bb * H + oh) * W + ow) * C + oc0 + ocl) = hv;
            }
        }
    }
}

// ================= ConvTranspose2d(k3,s2,p1,op1)+ELU via MFMA ======================
// in [b][Hi][Wi][IC], wp [OC][9][IC], out [b][2Hi][2Wi][OC]
template<int IC, int OC, int Hi, int Wi>
__launch_bounds__(256, 2)
__global__ void convt_mfma(const f16* __restrict__ in, const f16* __restrict__ wp,
                           const float* __restrict__ bias, f16* __restrict__ out) {
    constexpr int HT = 4, WT = 16;
    constexpr int PIXR = WT + 1;
    constexpr int ROWS = HT + 1;
    constexpr int XB = ROWS * PIXR * 80;
    __shared__ __align__(16) char lds[XB + 32 * 592];
    char* xlds = lds;
    char* wlds = lds + XB;

    const int tid = threadIdx.x;
    const int wid = tid >> 6, lane = tid & 63;
    const int ln15 = lane & 15, lg = lane >> 4;
    const int iloc = wid;
    const int bz = blockIdx.z;
    const int bb = bz / (OC / 32), ocg = bz % (OC / 32);
    const int oc0 = ocg * 32;
    const int i0 = blockIdx.y * HT, j0 = blockIdx.x * WT;

    f4 acc[4][2] = {};

    for (int icc = 0; icc < IC; icc += 32) {
        __syncthreads();
        for (int t = tid; t < ROWS * PIXR * 4; t += 256) {
            const int g = t & 3, pix = t >> 2;
            const int rr = pix / PIXR, ww = pix - rr * PIXR;
            const int gh = i0 + rr, gw = j0 + ww;
            h8 v = {};
            if (gh < Hi && gw < Wi)
                v = *(const h8*)(in + (((size_t)bb * Hi + gh) * Wi + gw) * IC + icc + g * 8);
            *(h8*)(xlds + pix * 80 + g * 16) = v;
        }
        for (int t = tid; t < 1152; t += 256) {
            const int g = t & 3, s = t >> 2;
            const int o = s / 9, tap = s - o * 9;
            h8 v = *(const h8*)(wp + ((size_t)(oc0 + o) * 9 + tap) * IC + icc + g * 8);
            *(h8*)(wlds + o * 592 + tap * 64 + g * 16) = v;
        }
        __syncthreads();

        h8 af[9][2];
        #pragma unroll
        for (int tap = 0; tap < 9; ++tap)
            #pragma unroll
            for (int mt = 0; mt < 2; ++mt)
                af[tap][mt] = *(const h8*)(wlds + (mt * 16 + ln15) * 592 + tap * 64 + lg * 16);

        h8 bf[2][2];
        #pragma unroll
        for (int a = 0; a < 2; ++a)
            #pragma unroll
            for (int b = 0; b < 2; ++b)
                bf[a][b] = *(const h8*)(xlds + ((iloc + a) * PIXR + ln15 + b) * 80 + lg * 16);

        #pragma unroll
        for (int p = 0; p < 4; ++p) {
            const int di = p >> 1, dj = p & 1;
            #pragma unroll
            for (int a = 0; a < 2; ++a) {
                if (a > di) continue;
                const int kh = 1 + di - 2 * a;
                #pragma unroll
                for (int b = 0; b < 2; ++b) {
                    if (b > dj) continue;
                    const int kw = 1 + dj - 2 * b;
                    const int tap = kh * 3 + kw;
                    acc[p][0] = __builtin_amdgcn_mfma_f32_16x16x32_f16(af[tap][0], bf[a][b], acc[p][0], 0, 0, 0);
                    acc[p][1] = __builtin_amdgcn_mfma_f32_16x16x32_f16(af[tap][1], bf[a][b], acc[p][1], 0, 0, 0);
                }
            }
        }
    }

    #pragma unroll
    for (int p = 0; p < 4; ++p) {
        const int orow = 2 * (i0 + iloc) + (p >> 1);
        const int ocol = 2 * (j0 + ln15) + (p & 1);
        #pragma unroll
        for (int mt = 0; mt < 2; ++mt) {
            const int ocl = mt * 16 + lg * 4;
            const float4 b4 = *(const float4*)(bias + oc0 + ocl);
            const f4 v = acc[p][mt];
            h4 hv = {(f16)elu_f(v.x + b4.x), (f16)elu_f(v.y + b4.y),
                     (f16)elu_f(v.z + b4.z), (f16)elu_f(v.w + b4.w)};
            *(h4*)(out + (((size_t)bb * (2 * Hi) + orow) * (2 * Wi) + ocol) * OC + oc0 + ocl) = hv;
        }
    }
}

// ================= Gram partials: x3cf f16 [b][32][N], sem f32 [b][32][N] ==========
__launch_bounds__(256)
__global__ void gram_partial_k(const f16* __restrict__ x3, const float* __restrict__ sem,
                               float* __restrict__ part, float* __restrict__ sums) {
    const int b = blockIdx.y, chunk = blockIdx.x, tid = threadIdx.x;
    const int c0 = tid >> 4, d0 = tid & 15;
    __shared__ float xs[32][132];
    __shared__ float ss[32][132];
    const size_t N = 65536;
    const f16*   xb = x3  + (size_t)b * 32 * N + (size_t)chunk * 2048;
    const float* sb = sem + (size_t)b * 32 * N + (size_t)chunk * 2048;
    float a00 = 0.f, a01 = 0.f, a10 = 0.f, a11 = 0.f;
    float sxacc = 0.f, ssacc = 0.f;

    for (int sub = 0; sub < 16; ++sub) {
        __syncthreads();
        for (int t = tid; t < 1024; t += 256) {
            const int arr = t >> 9, s = t & 511, r = s >> 4, c8 = (s & 15) << 3;
            if (arr == 0) {
                const h8 v = *(const h8*)(xb + (size_t)r * N + sub * 128 + c8);
                #pragma unroll
                for (int q = 0; q < 8; ++q) xs[r][c8 + q] = (float)v[q];
            } else {
                const float* sp = sb + (size_t)r * N + sub * 128 + c8;
                *(float4*)&ss[r][c8]     = *(const float4*)sp;
                *(float4*)&ss[r][c8 + 4] = *(const float4*)(sp + 4);
            }
        }
        __syncthreads();
        #pragma unroll 8
        for (int j4 = 0; j4 < 32; ++j4) {
            const float4 xa = *(const float4*)&xs[c0][j4 * 4];
            const float4 xc = *(const float4*)&xs[c0 + 16][j4 * 4];
            const float4 sa = *(const float4*)&ss[d0][j4 * 4];
            const float4 sc = *(const float4*)&ss[d0 + 16][j4 * 4];
            a00 = fmaf(xa.x, sa.x, fmaf(xa.y, sa.y, fmaf(xa.z, sa.z, fmaf(xa.w, sa.w, a00))));
            a01 = fmaf(xa.x, sc.x, fmaf(xa.y, sc.y, fmaf(xa.z, sc.z, fmaf(xa.w, sc.w, a01))));
            a10 = fmaf(xc.x, sa.x, fmaf(xc.y, sa.y, fmaf(xc.z, sa.z, fmaf(xc.w, sa.w, a10))));
            a11 = fmaf(xc.x, sc.x, fmaf(xc.y, sc.y, fmaf(xc.z, sc.z, fmaf(xc.w, sc.w, a11))));
        }
        if (tid < 128) {
            const int r = (tid & 63) >> 1, half = tid & 1;
            const float* src = (tid < 64) ? &xs[r][half * 64] : &ss[r][half * 64];
            float s = 0.f;
            #pragma unroll
            for (int q = 0; q < 64; ++q) s += src[q];
            if (tid < 64) sxacc += s; else ssacc += s;
        }
    }
    float* pb = part + ((size_t)b * 32 + chunk) * 1024;
    pb[c0 * 32 + d0]             = a00;
    pb[c0 * 32 + d0 + 16]        = a01;
    pb[(c0 + 16) * 32 + d0]      = a10;
    pb[(c0 + 16) * 32 + d0 + 16] = a11;
    if (tid < 128) {
        const int r = (tid & 63) >> 1;
        const float mine = (tid < 64) ? sxacc : ssacc;
        const float tot = mine + __shfl_xor(mine, 1);
        if ((tid & 1) == 0)
            sums[((size_t)b * 32 + chunk) * 64 + (tid < 64 ? r : 32 + r)] = tot;
    }
}

// ================= reduce Gram -> softmax(Wa G Wa^T + bias) -> u, cb ===============
__launch_bounds__(256)
__global__ void attn_finish_k(const float* __restrict__ part, const float* __restrict__ sums,
                              const float* __restrict__ wa, const float* __restrict__ ba,
                              const float* __restrict__ wf, const float* __restrict__ bf,
                              float* __restrict__ u, float* __restrict__ cb) {
    __shared__ float G[32][33];
    __shared__ float T[16][33];
    __shared__ float A[16][17];
    __shared__ float Sx[32], Ss[32], px[16], ps[16], v[16];
    const int tid = threadIdx.x;
    for (int b = 0; b < 8; ++b) {
        __syncthreads();
        for (int t = tid; t < 1024; t += 256) {
            float s = 0.f;
            for (int ch = 0; ch < 32; ++ch) s += part[((size_t)b * 32 + ch) * 1024 + t];
            G[t >> 5][t & 31] = s;
        }
        if (tid < 64) {
            float s = 0.f;
            for (int ch = 0; ch < 32; ++ch) s += sums[((size_t)b * 32 + ch) * 64 + tid];
            if (tid < 32) Sx[tid] = s; else Ss[tid - 32] = s;
        }
        __syncthreads();
        for (int t = tid; t < 512; t += 256) {
            const int c = t >> 5, f = t & 31;
            float s = 0.f;
            #pragma unroll
            for (int e = 0; e < 32; ++e) s = fmaf(wa[c * 32 + e], G[e][f], s);
            T[c][f] = s;
        }
        if (tid < 32) {
            const int c = tid & 15;
            const float* S = (tid < 16) ? Sx : Ss;
            float s = 0.f;
            #pragma unroll
            for (int e = 0; e < 32; ++e) s = fmaf(wa[c * 32 + e], S[e], s);
            if (tid < 16) px[c] = s; else ps[c] = s;
        }
        __syncthreads();
        if (tid < 256) {
            if (tid < 16 * 16) {
                const int c = tid >> 4, d = tid & 15;
                float s = 0.f;
                #pragma unroll
                for (int f2 = 0; f2 < 32; ++f2) s = fmaf(T[c][f2], wa[d * 32 + f2], s);
                s += px[c] * ba[d] + ba[c] * ps[d] + 65536.f * ba[c] * ba[d];
                A[c][d] = s;
            }
        }
        __syncthreads();
        if (tid < 16) {
            float m = A[tid][0];
            #pragma unroll
            for (int d = 1; d < 16; ++d) m = fmaxf(m, A[tid][d]);
            float s = 0.f;
            #pragma unroll
            for (int d = 0; d < 16; ++d) { const float e = expf(A[tid][d] - m); A[tid][d] = e; s += e; }
            const float inv = 1.f / s;
            #pragma unroll
            for (int d = 0; d < 16; ++d) A[tid][d] *= inv;
        }
        __syncthreads();
        if (tid < 16) {
            float s = wf[tid];
            #pragma unroll
            for (int c = 0; c < 16; ++c) s = fmaf(wf[c], A[c][tid], s);
            v[tid] = s;
        }
        __syncthreads();
        if (tid < 32) {
            float s = 0.f;
            #pragma unroll
            for (int d = 0; d < 16; ++d) s = fmaf(v[d], wa[d * 32 + tid], s);
            u[b * 32 + tid] = s;
        }
        if (tid == 0) {
            float s2 = bf[0];
            #pragma unroll
            for (int d = 0; d < 16; ++d) s2 = fmaf(v[d], ba[d], s2);
            cb[b] = s2;
        }
    }
}

// ================= final: out[b][n] = sigmoid(cb + sum_e u[e]*x3cf[e][n]) ==========
__launch_bounds__(256)
__global__ void final_k(const f16* __restrict__ x3, const float* __restrict__ u,
                        const float* __restrict__ cb, float* __restrict__ out) {
    const int b = blockIdx.y;
    const int nn = blockIdx.x * 256 + threadIdx.x;
    const size_t N = 65536;
    const f16* xb = x3 + (size_t)b * 32 * N + nn;
    float acc = cb[b];
    #pragma unroll
    for (int e = 0; e < 32; ++e) acc = fmaf(u[b * 32 + e], (float)xb[(size_t)e * N], acc);
    out[(size_t)b * N + nn] = sigmoid_f(acc);
}

extern "C" void kernel_launch(void* const* d_in, const int* in_sizes, int n_in,
                              void* d_out, int out_size, void* d_ws, size_t ws_size,
                              hipStream_t stream) {
    const float* enc   = (const float*)d_in[0];
    const float* sem   = (const float*)d_in[1];
    const float* wt0   = (const float*)d_in[2];
    const float* bt0   = (const float*)d_in[3];
    const float* wc0   = (const float*)d_in[4];
    const float* bc0   = (const float*)d_in[5];
    const float* wt1   = (const float*)d_in[6];
    const float* bt1   = (const float*)d_in[7];
    const float* wc1   = (const float*)d_in[8];
    const float* bc1   = (const float*)d_in[9];
    const float* wt2   = (const float*)d_in[10];
    const float* bt2   = (const float*)d_in[11];
    const float* wc2   = (const float*)d_in[12];
    const float* bc2   = (const float*)d_in[13];
    const float* wt3   = (const float*)d_in[14];
    const float* bt3   = (const float*)d_in[15];
    const float* wc3   = (const float*)d_in[16];
    const float* bc3   = (const float*)d_in[17];
    const float* wattn = (const float*)d_in[18];
    const float* battn = (const float*)d_in[19];
    const float* wfin  = (const float*)d_in[20];
    const float* bfin  = (const float*)d_in[21];

    char* W = (char*)d_ws;
    f16*   actA   = (f16*)(W + 0);            // 32 MB
    f16*   actB   = (f16*)(W + 33554432);     // 32 MB
    f16*   x3cf   = (f16*)(W + 67108864);     // 32 MB, channel-first
    f16*   wp     = (f16*)(W + 100663296);    // 4.7 MB
    f16*   enc_cl = (f16*)(W + 105906176);    // 2 MB
    float* part   = (float*)(W + 108003328);  // 1 MB
    float* sums   = (float*)(W + 109051904);  // 64 KB
    float* u      = (float*)(W + 109117440);
    float* cb     = (float*)(W + 109118464);
    float* out    = (float*)d_out;

    // weight prep (f16 [oc][tap][ic]) + enc transpose to channel-last f16
    P8 p;
    p.d[0] = {wt0, 0u,       256, 512, 1};
    p.d[1] = {wc0, 1179648u, 256, 256, 0};
    p.d[2] = {wt1, 1769472u, 128, 256, 1};
    p.d[3] = {wc1, 2064384u, 128, 128, 0};
    p.d[4] = {wt2, 2211840u,  64, 128, 1};
    p.d[5] = {wc2, 2285568u,  64,  64, 0};
    p.d[6] = {wt3, 2322432u,  32,  64, 1};
    p.d[7] = {wc3, 2340864u,  32,  32, 0};
    prep_weights_k<<<9180, 256, 0, stream>>>(p, wp);
    enc_transpose_k<<<128, 256, 0, stream>>>(enc, enc_cl);

    // decoder (channel-last f16 activations)
    convt_mfma<512, 256, 16, 16>    <<<dim3(1, 4, 64),  256, 0, stream>>>(enc_cl, wp,           bt0, actA);
    conv3_mfma<256, 32, 32, 8, 32, 2, false><<<dim3(1, 4, 64),  256, 0, stream>>>(actA, wp + 1179648, bc0, actB, nullptr);
    convt_mfma<256, 128, 32, 32>    <<<dim3(2, 8, 32),  256, 0, stream>>>(actB, wp + 1769472, bt1, actA);
    conv3_mfma<128, 64, 64, 4, 64, 4, false><<<dim3(1, 16, 32), 256, 0, stream>>>(actA, wp + 2064384, bc1, actB, nullptr);
    convt_mfma<128, 64, 64, 64>     <<<dim3(4, 16, 16), 256, 0, stream>>>(actB, wp + 2211840, bt2, actA);
    conv3_mfma<64, 128, 128, 4, 64, 4, false><<<dim3(2, 32, 16), 256, 0, stream>>>(actA, wp + 2285568, bc2, actB, nullptr);
    convt_mfma<64, 32, 128, 128>    <<<dim3(8, 32, 8),  256, 0, stream>>>(actB, wp + 2322432, bt3, actA);
    conv3_mfma<32, 256, 256, 4, 64, 4, true><<<dim3(4, 64, 8),  256, 0, stream>>>(actA, wp + 2340864, bc3, nullptr, x3cf);

    // attention tail (folded into per-batch u, cb) + final
    gram_partial_k<<<dim3(32, 8), 256, 0, stream>>>(x3cf, sem, part, sums);
    attn_finish_k<<<1, 256, 0, stream>>>(part, sums, wattn, battn, wfin, bfin, u, cb);
    final_k<<<dim3(256, 8), 256, 0, stream>>>(x3cf, u, cb, out);
}

// Round 4
// 344.237 us; speedup vs baseline: 12.0451x; 1.3229x over previous
//
#include <hip/hip_runtime.h>
#include <hip/hip_bf16.h>
#include <math.h>

typedef _Float16 f16;
typedef _Float16 h8 __attribute__((ext_vector_type(8)));
typedef _Float16 h4 __attribute__((ext_vector_type(4)));
typedef float    f4 __attribute__((ext_vector_type(4)));

__device__ __forceinline__ float elu_f(float v) { return v > 0.f ? v : expm1f(v); }
__device__ __forceinline__ float sigmoid_f(float v) { return 1.f / (1.f + expf(-v)); }

// ================= weight prep: all 8 tensors -> f16 [oc][tap][ic] =================
struct PrepDesc { const float* src; unsigned dstOff; int OC; int IC; int tr; };
struct P8 { PrepDesc d[8]; };

__global__ void prep_weights_k(P8 p, f16* __restrict__ wp) {
    unsigned idx = blockIdx.x * 256u + threadIdx.x;
    for (int s = 0; s < 8; ++s) {
        const int IC = p.d[s].IC, OC = p.d[s].OC;
        const unsigned cnt = (unsigned)(OC * 9 * IC);
        if (idx < cnt) {
            const int oc = idx / (9u * IC);
            const unsigned r = idx - oc * (9u * IC);
            const int tap = r / IC, ic = r - tap * IC;
            const float v = p.d[s].tr ? p.d[s].src[((size_t)ic * OC + oc) * 9 + tap]
                                      : p.d[s].src[((size_t)oc * IC + ic) * 9 + tap];
            wp[p.d[s].dstOff + idx] = (f16)v;
            return;
        }
        idx -= cnt;
    }
}

// ================= enc transpose: [8][512][16][16] f32 -> [8][256px][512] f16 ======
__global__ void enc_transpose_k(const float* __restrict__ enc, f16* __restrict__ out) {
    __shared__ float ts[32][257];
    const int b = blockIdx.x >> 4, cg = blockIdx.x & 15;
    const int tid = threadIdx.x;
    #pragma unroll
    for (int i = 0; i < 32; ++i)
        ts[i][tid] = enc[((size_t)(b * 512 + cg * 32 + i)) * 256 + tid];
    __syncthreads();
    #pragma unroll
    for (int k = 0; k < 4; ++k) {
        h8 v;
        #pragma unroll
        for (int q = 0; q < 8; ++q) v[q] = (f16)ts[k * 8 + q][tid];
        *(h8*)(out + ((size_t)(b * 256 + tid)) * 512 + cg * 32 + k * 8) = v;
    }
}

// ================= Conv2d(k3,p1)+ELU via MFMA, channel-last f16 ====================
template<int C, int H, int W, int HT, int WT, int NWN, bool CF_OUT>
__launch_bounds__(256, 2)
__global__ void conv3_mfma(const f16* __restrict__ in, const f16* __restrict__ wp,
                           const float* __restrict__ bias, f16* __restrict__ out,
                           f16* __restrict__ outcf) {
    constexpr int NWR = 4 / NWN;
    constexpr int RH  = HT / NWR;
    constexpr int PIXR = WT + 2;
    constexpr int ROWS = HT + 2;
    constexpr int XB = ROWS * PIXR * 80;
    __shared__ __align__(16) char lds[XB + 32 * 592];
    char* xlds = lds;
    char* wlds = lds + XB;

    const int tid = threadIdx.x;
    const int wid = tid >> 6, lane = tid & 63;
    const int ln15 = lane & 15, lg = lane >> 4;
    const int ni = wid % NWN, ri = wid / NWN;
    const int bz = blockIdx.z;
    const int bb = bz / (C / 32), ocg = bz % (C / 32);
    const int oc0 = ocg * 32;
    const int h0 = blockIdx.y * HT, w0 = blockIdx.x * WT;
    const int colb = ni * 16 + ln15;

    f4 acc[RH][2] = {};

    for (int icc = 0; icc < C; icc += 32) {
        __syncthreads();
        for (int t = tid; t < ROWS * PIXR * 4; t += 256) {
            const int g = t & 3, pix = t >> 2;
            const int rr = pix / PIXR, ww = pix - rr * PIXR;
            const int gh = h0 - 1 + rr, gw = w0 - 1 + ww;
            h8 v = {};
            if (gh >= 0 && gh < H && gw >= 0 && gw < W)
                v = *(const h8*)(in + (((size_t)bb * H + gh) * W + gw) * C + icc + g * 8);
            *(h8*)(xlds + pix * 80 + g * 16) = v;
        }
        for (int t = tid; t < 1152; t += 256) {
            const int g = t & 3, s = t >> 2;
            const int o = s / 9, tap = s - o * 9;
            h8 v = *(const h8*)(wp + ((size_t)(oc0 + o) * 9 + tap) * C + icc + g * 8);
            *(h8*)(wlds + o * 592 + tap * 64 + g * 16) = v;
        }
        __syncthreads();

        h8 af[9][2];
        #pragma unroll
        for (int tap = 0; tap < 9; ++tap)
            #pragma unroll
            for (int mt = 0; mt < 2; ++mt)
                af[tap][mt] = *(const h8*)(wlds + (mt * 16 + ln15) * 592 + tap * 64 + lg * 16);

        #pragma unroll
        for (int r = 0; r < RH; ++r) {
            const int orow = ri * RH + r;
            #pragma unroll
            for (int dh = 0; dh < 3; ++dh) {
                #pragma unroll
                for (int dw = 0; dw < 3; ++dw) {
                    const h8 bf = *(const h8*)(xlds + ((orow + dh) * PIXR + colb + dw) * 80 + lg * 16);
                    acc[r][0] = __builtin_amdgcn_mfma_f32_16x16x32_f16(af[dh * 3 + dw][0], bf, acc[r][0], 0, 0, 0);
                    acc[r][1] = __builtin_amdgcn_mfma_f32_16x16x32_f16(af[dh * 3 + dw][1], bf, acc[r][1], 0, 0, 0);
                }
            }
        }
    }

    #pragma unroll
    for (int r = 0; r < RH; ++r) {
        const int oh = h0 + ri * RH + r;
        const int ow = w0 + colb;
        #pragma unroll
        for (int mt = 0; mt < 2; ++mt) {
            const int ocl = mt * 16 + lg * 4;
            const float4 b4 = *(const float4*)(bias + oc0 + ocl);
            const f4 v = acc[r][mt];
            const float e0 = elu_f(v.x + b4.x), e1 = elu_f(v.y + b4.y);
            const float e2 = elu_f(v.z + b4.z), e3 = elu_f(v.w + b4.w);
            if constexpr (CF_OUT) {
                const size_t n = (size_t)oh * W + ow;
                const size_t plane = (size_t)H * W;
                outcf[((size_t)bb * C + oc0 + ocl + 0) * plane + n] = (f16)e0;
                outcf[((size_t)bb * C + oc0 + ocl + 1) * plane + n] = (f16)e1;
                outcf[((size_t)bb * C + oc0 + ocl + 2) * plane + n] = (f16)e2;
                outcf[((size_t)bb * C + oc0 + ocl + 3) * plane + n] = (f16)e3;
            } else {
                h4 hv = {(f16)e0, (f16)e1, (f16)e2, (f16)e3};
                *(h4*)(out + (((size_t)bb * H + oh) * W + ow) * C + oc0 + ocl) = hv;
            }
        }
    }
}

// ================= ConvTranspose2d(k3,s2,p1,op1)+ELU via MFMA ======================
template<int IC, int OC, int Hi, int Wi>
__launch_bounds__(256, 2)
__global__ void convt_mfma(const f16* __restrict__ in, const f16* __restrict__ wp,
                           const float* __restrict__ bias, f16* __restrict__ out) {
    constexpr int HT = 4, WT = 16;
    constexpr int PIXR = WT + 1;
    constexpr int ROWS = HT + 1;
    constexpr int XB = ROWS * PIXR * 80;
    __shared__ __align__(16) char lds[XB + 32 * 592];
    char* xlds = lds;
    char* wlds = lds + XB;

    const int tid = threadIdx.x;
    const int wid = tid >> 6, lane = tid & 63;
    const int ln15 = lane & 15, lg = lane >> 4;
    const int iloc = wid;
    const int bz = blockIdx.z;
    const int bb = bz / (OC / 32), ocg = bz % (OC / 32);
    const int oc0 = ocg * 32;
    const int i0 = blockIdx.y * HT, j0 = blockIdx.x * WT;

    f4 acc[4][2] = {};

    for (int icc = 0; icc < IC; icc += 32) {
        __syncthreads();
        for (int t = tid; t < ROWS * PIXR * 4; t += 256) {
            const int g = t & 3, pix = t >> 2;
            const int rr = pix / PIXR, ww = pix - rr * PIXR;
            const int gh = i0 + rr, gw = j0 + ww;
            h8 v = {};
            if (gh < Hi && gw < Wi)
                v = *(const h8*)(in + (((size_t)bb * Hi + gh) * Wi + gw) * IC + icc + g * 8);
            *(h8*)(xlds + pix * 80 + g * 16) = v;
        }
        for (int t = tid; t < 1152; t += 256) {
            const int g = t & 3, s = t >> 2;
            const int o = s / 9, tap = s - o * 9;
            h8 v = *(const h8*)(wp + ((size_t)(oc0 + o) * 9 + tap) * IC + icc + g * 8);
            *(h8*)(wlds + o * 592 + tap * 64 + g * 16) = v;
        }
        __syncthreads();

        h8 af[9][2];
        #pragma unroll
        for (int tap = 0; tap < 9; ++tap)
            #pragma unroll
            for (int mt = 0; mt < 2; ++mt)
                af[tap][mt] = *(const h8*)(wlds + (mt * 16 + ln15) * 592 + tap * 64 + lg * 16);

        h8 bf[2][2];
        #pragma unroll
        for (int a = 0; a < 2; ++a)
            #pragma unroll
            for (int b = 0; b < 2; ++b)
                bf[a][b] = *(const h8*)(xlds + ((iloc + a) * PIXR + ln15 + b) * 80 + lg * 16);

        #pragma unroll
        for (int p = 0; p < 4; ++p) {
            const int di = p >> 1, dj = p & 1;
            #pragma unroll
            for (int a = 0; a < 2; ++a) {
                if (a > di) continue;
                const int kh = 1 + di - 2 * a;
                #pragma unroll
                for (int b = 0; b < 2; ++b) {
                    if (b > dj) continue;
                    const int kw = 1 + dj - 2 * b;
                    const int tap = kh * 3 + kw;
                    acc[p][0] = __builtin_amdgcn_mfma_f32_16x16x32_f16(af[tap][0], bf[a][b], acc[p][0], 0, 0, 0);
                    acc[p][1] = __builtin_amdgcn_mfma_f32_16x16x32_f16(af[tap][1], bf[a][b], acc[p][1], 0, 0, 0);
                }
            }
        }
    }

    #pragma unroll
    for (int p = 0; p < 4; ++p) {
        const int orow = 2 * (i0 + iloc) + (p >> 1);
        const int ocol = 2 * (j0 + ln15) + (p & 1);
        #pragma unroll
        for (int mt = 0; mt < 2; ++mt) {
            const int ocl = mt * 16 + lg * 4;
            const float4 b4 = *(const float4*)(bias + oc0 + ocl);
            const f4 v = acc[p][mt];
            h4 hv = {(f16)elu_f(v.x + b4.x), (f16)elu_f(v.y + b4.y),
                     (f16)elu_f(v.z + b4.z), (f16)elu_f(v.w + b4.w)};
            *(h4*)(out + (((size_t)bb * (2 * Hi) + orow) * (2 * Wi) + ocol) * OC + oc0 + ocl) = hv;
        }
    }
}

// ================= Gram via MFMA, LDS-free fragments ===============================
// x3 f16 [8][32][N], sem f32 [8][32][N] -> part[b][128][1024] (c*32+d), sums[b][128][64]
#define KCH 128
__launch_bounds__(256)
__global__ void gram_mfma_k(const f16* __restrict__ x3, const float* __restrict__ sem,
                            float* __restrict__ part, float* __restrict__ sums) {
    __shared__ float pl[4][1024];
    __shared__ float sl[4][64];
    const int b = blockIdx.y, kc = blockIdx.x;
    const int tid = threadIdx.x, wid = tid >> 6, lane = tid & 63;
    const int row = lane & 15, kg = lane >> 4;
    const size_t N = 65536;
    const int k0 = kc * (65536 / KCH) + wid * (65536 / KCH / 4);   // 512/chunk, 128/wave

    const f16*   xa = x3  + ((size_t)b * 32 + row) * N + k0 + kg * 8;
    const float* sb = sem + ((size_t)b * 32 + row) * N + k0 + kg * 8;

    f4 acc00 = {}, acc01 = {}, acc10 = {}, acc11 = {};
    float sx0 = 0.f, sx1 = 0.f, ss0 = 0.f, ss1 = 0.f;

    #pragma unroll
    for (int s = 0; s < 4; ++s) {
        const int ko = s * 32;
        const h8 a0 = *(const h8*)(xa + ko);
        const h8 a1 = *(const h8*)(xa + 16 * N + ko);
        const float4 f0 = *(const float4*)(sb + ko);
        const float4 f1 = *(const float4*)(sb + ko + 4);
        const float4 g0 = *(const float4*)(sb + 16 * N + ko);
        const float4 g1 = *(const float4*)(sb + 16 * N + ko + 4);
        const h8 b0 = {(f16)f0.x, (f16)f0.y, (f16)f0.z, (f16)f0.w,
                       (f16)f1.x, (f16)f1.y, (f16)f1.z, (f16)f1.w};
        const h8 b1 = {(f16)g0.x, (f16)g0.y, (f16)g0.z, (f16)g0.w,
                       (f16)g1.x, (f16)g1.y, (f16)g1.z, (f16)g1.w};
        acc00 = __builtin_amdgcn_mfma_f32_16x16x32_f16(a0, b0, acc00, 0, 0, 0);
        acc01 = __builtin_amdgcn_mfma_f32_16x16x32_f16(a0, b1, acc01, 0, 0, 0);
        acc10 = __builtin_amdgcn_mfma_f32_16x16x32_f16(a1, b0, acc10, 0, 0, 0);
        acc11 = __builtin_amdgcn_mfma_f32_16x16x32_f16(a1, b1, acc11, 0, 0, 0);
        #pragma unroll
        for (int q = 0; q < 8; ++q) { sx0 += (float)a0[q]; sx1 += (float)a1[q]; }
        ss0 += (f0.x + f0.y + f0.z + f0.w) + (f1.x + f1.y + f1.z + f1.w);
        ss1 += (g0.x + g0.y + g0.z + g0.w) + (g1.x + g1.y + g1.z + g1.w);
    }

    // reduce channel sums across kg groups (lanes sharing `row`)
    sx0 += __shfl_xor(sx0, 16); sx0 += __shfl_xor(sx0, 32);
    sx1 += __shfl_xor(sx1, 16); sx1 += __shfl_xor(sx1, 32);
    ss0 += __shfl_xor(ss0, 16); ss0 += __shfl_xor(ss0, 32);
    ss1 += __shfl_xor(ss1, 16); ss1 += __shfl_xor(ss1, 32);

    // per-wave partial gram to LDS: entry = c*32 + d  (c from A-row, d from B-row)
    #pragma unroll
    for (int reg = 0; reg < 4; ++reg) {
        const int c0 = 4 * kg + reg;
        pl[wid][c0 * 32 + row]               = acc00[reg];
        pl[wid][c0 * 32 + 16 + row]          = acc01[reg];
        pl[wid][(16 + c0) * 32 + row]        = acc10[reg];
        pl[wid][(16 + c0) * 32 + 16 + row]   = acc11[reg];
    }
    if (lane < 16) {
        sl[wid][row]      = sx0;
        sl[wid][16 + row] = sx1;
        sl[wid][32 + row] = ss0;
        sl[wid][48 + row] = ss1;
    }
    __syncthreads();

    float* pb = part + ((size_t)b * KCH + kc) * 1024;
    #pragma unroll
    for (int t = tid; t < 1024; t += 256)
        pb[t] = pl[0][t] + pl[1][t] + pl[2][t] + pl[3][t];
    if (tid < 64)
        sums[((size_t)b * KCH + kc) * 64 + tid] = sl[0][tid] + sl[1][tid] + sl[2][tid] + sl[3][tid];
}

// ================= per-batch: reduce -> softmax(Wa G Wa^T + bias) -> u, cb =========
__launch_bounds__(256)
__global__ void attn_finish_v3(const float* __restrict__ part, const float* __restrict__ sums,
                               const float* __restrict__ wa, const float* __restrict__ ba,
                               const float* __restrict__ wf, const float* __restrict__ bf,
                               float* __restrict__ u, float* __restrict__ cb) {
    __shared__ float G[32][33];
    __shared__ float T[16][33];
    __shared__ float A[16][17];
    __shared__ float Sx[32], Ss[32], px[16], ps[16], v[16];
    const int b = blockIdx.x, tid = threadIdx.x;

    float a4[4] = {0.f, 0.f, 0.f, 0.f};
    for (int p = 0; p < KCH; ++p) {
        const float* pp = part + ((size_t)b * KCH + p) * 1024 + tid;
        a4[0] += pp[0]; a4[1] += pp[256]; a4[2] += pp[512]; a4[3] += pp[768];
    }
    #pragma unroll
    for (int q = 0; q < 4; ++q) {
        const int t = tid + q * 256;
        G[t >> 5][t & 31] = a4[q];
    }
    if (tid < 64) {
        float s = 0.f;
        for (int p = 0; p < KCH; ++p) s += sums[((size_t)b * KCH + p) * 64 + tid];
        if (tid < 32) Sx[tid] = s; else Ss[tid - 32] = s;
    }
    __syncthreads();
    for (int t = tid; t < 512; t += 256) {               // T = Wa * G
        const int c = t >> 5, f = t & 31;
        float s = 0.f;
        #pragma unroll
        for (int e = 0; e < 32; ++e) s = fmaf(wa[c * 32 + e], G[e][f], s);
        T[c][f] = s;
    }
    if (tid < 32) {                                      // px = Wa*Sx, ps = Wa*Ss
        const int c = tid & 15;
        const float* S = (tid < 16) ? Sx : Ss;
        float s = 0.f;
        #pragma unroll
        for (int e = 0; e < 32; ++e) s = fmaf(wa[c * 32 + e], S[e], s);
        if (tid < 16) px[c] = s; else ps[c] = s;
    }
    __syncthreads();
    if (tid < 256) {
        const int c = tid >> 4, d = tid & 15;            // A[c][d], 256 threads exactly
        float s = 0.f;
        #pragma unroll
        for (int f2 = 0; f2 < 32; ++f2) s = fmaf(T[c][f2], wa[d * 32 + f2], s);
        s += px[c] * ba[d] + ba[c] * ps[d] + 65536.f * ba[c] * ba[d];
        A[c][d] = s;
    }
    __syncthreads();
    if (tid < 16) {                                      // row softmax
        float m = A[tid][0];
        #pragma unroll
        for (int d = 1; d < 16; ++d) m = fmaxf(m, A[tid][d]);
        float s = 0.f;
        #pragma unroll
        for (int d = 0; d < 16; ++d) { const float e = expf(A[tid][d] - m); A[tid][d] = e; s += e; }
        const float inv = 1.f / s;
        #pragma unroll
        for (int d = 0; d < 16; ++d) A[tid][d] *= inv;
    }
    __syncthreads();
    if (tid < 16) {                                      // v[d] = wf[d] + sum_c wf[c]*A[c][d]
        float s = wf[tid];
        #pragma unroll
        for (int c = 0; c < 16; ++c) s = fmaf(wf[c], A[c][tid], s);
        v[tid] = s;
    }
    __syncthreads();
    if (tid < 32) {                                      // u[e] = sum_d v[d]*wa[d][e]
        float s = 0.f;
        #pragma unroll
        for (int d = 0; d < 16; ++d) s = fmaf(v[d], wa[d * 32 + tid], s);
        u[b * 32 + tid] = s;
    }
    if (tid == 0) {
        float s2 = bf[0];
        #pragma unroll
        for (int d = 0; d < 16; ++d) s2 = fmaf(v[d], ba[d], s2);
        cb[b] = s2;
    }
}

// ================= final: out[b][n] = sigmoid(cb + sum_e u[e]*x3cf[e][n]) ==========
__launch_bounds__(256)
__global__ void final_k(const f16* __restrict__ x3, const float* __restrict__ u,
                        const float* __restrict__ cb, float* __restrict__ out) {
    const int b = blockIdx.y;
    const int nn = blockIdx.x * 256 + threadIdx.x;
    const size_t N = 65536;
    const f16* xb = x3 + (size_t)b * 32 * N + nn;
    float acc = cb[b];
    #pragma unroll
    for (int e = 0; e < 32; ++e) acc = fmaf(u[b * 32 + e], (float)xb[(size_t)e * N], acc);
    out[(size_t)b * N + nn] = sigmoid_f(acc);
}

extern "C" void kernel_launch(void* const* d_in, const int* in_sizes, int n_in,
                              void* d_out, int out_size, void* d_ws, size_t ws_size,
                              hipStream_t stream) {
    const float* enc   = (const float*)d_in[0];
    const float* sem   = (const float*)d_in[1];
    const float* wt0   = (const float*)d_in[2];
    const float* bt0   = (const float*)d_in[3];
    const float* wc0   = (const float*)d_in[4];
    const float* bc0   = (const float*)d_in[5];
    const float* wt1   = (const float*)d_in[6];
    const float* bt1   = (const float*)d_in[7];
    const float* wc1   = (const float*)d_in[8];
    const float* bc1   = (const float*)d_in[9];
    const float* wt2   = (const float*)d_in[10];
    const float* bt2   = (const float*)d_in[11];
    const float* wc2   = (const float*)d_in[12];
    const float* bc2   = (const float*)d_in[13];
    const float* wt3   = (const float*)d_in[14];
    const float* bt3   = (const float*)d_in[15];
    const float* wc3   = (const float*)d_in[16];
    const float* bc3   = (const float*)d_in[17];
    const float* wattn = (const float*)d_in[18];
    const float* battn = (const float*)d_in[19];
    const float* wfin  = (const float*)d_in[20];
    const float* bfin  = (const float*)d_in[21];

    char* W = (char*)d_ws;
    f16*   actA   = (f16*)(W + 0);            // 32 MB
    f16*   actB   = (f16*)(W + 33554432);     // 32 MB
    f16*   x3cf   = (f16*)(W + 67108864);     // 32 MB, channel-first
    f16*   wp     = (f16*)(W + 100663296);    // 4.7 MB
    f16*   enc_cl = (f16*)(W + 105906176);    // 2 MB
    float* part   = (float*)(W + 108003328);  // 8*128*1024*4 = 4 MB
    float* sums   = (float*)(W + 112197632);  // 8*128*64*4 = 256 KB
    float* u      = (float*)(W + 112459776);
    float* cb     = (float*)(W + 112460800);
    float* out    = (float*)d_out;

    P8 p;
    p.d[0] = {wt0, 0u,       256, 512, 1};
    p.d[1] = {wc0, 1179648u, 256, 256, 0};
    p.d[2] = {wt1, 1769472u, 128, 256, 1};
    p.d[3] = {wc1, 2064384u, 128, 128, 0};
    p.d[4] = {wt2, 2211840u,  64, 128, 1};
    p.d[5] = {wc2, 2285568u,  64,  64, 0};
    p.d[6] = {wt3, 2322432u,  32,  64, 1};
    p.d[7] = {wc3, 2340864u,  32,  32, 0};
    prep_weights_k<<<9180, 256, 0, stream>>>(p, wp);
    enc_transpose_k<<<128, 256, 0, stream>>>(enc, enc_cl);

    convt_mfma<512, 256, 16, 16>    <<<dim3(1, 4, 64),  256, 0, stream>>>(enc_cl, wp,           bt0, actA);
    conv3_mfma<256, 32, 32, 8, 32, 2, false><<<dim3(1, 4, 64),  256, 0, stream>>>(actA, wp + 1179648, bc0, actB, nullptr);
    convt_mfma<256, 128, 32, 32>    <<<dim3(2, 8, 32),  256, 0, stream>>>(actB, wp + 1769472, bt1, actA);
    conv3_mfma<128, 64, 64, 4, 64, 4, false><<<dim3(1, 16, 32), 256, 0, stream>>>(actA, wp + 2064384, bc1, actB, nullptr);
    convt_mfma<128, 64, 64, 64>     <<<dim3(4, 16, 16), 256, 0, stream>>>(actB, wp + 2211840, bt2, actA);
    conv3_mfma<64, 128, 128, 4, 64, 4, false><<<dim3(2, 32, 16), 256, 0, stream>>>(actA, wp + 2285568, bc2, actB, nullptr);
    convt_mfma<64, 32, 128, 128>    <<<dim3(8, 32, 8),  256, 0, stream>>>(actB, wp + 2322432, bt3, actA);
    conv3_mfma<32, 256, 256, 4, 64, 4, true><<<dim3(4, 64, 8),  256, 0, stream>>>(actA, wp + 2340864, bc3, nullptr, x3cf);

    gram_mfma_k<<<dim3(KCH, 8), 256, 0, stream>>>(x3cf, sem, part, sums);
    attn_finish_v3<<<8, 256, 0, stream>>>(part, sums, wattn, battn, wfin, bfin, u, cb);
    final_k<<<dim3(256, 8), 256, 0, stream>>>(x3cf, u, cb, out);
}

// Round 5
// 289.856 us; speedup vs baseline: 14.3050x; 1.1876x over previous
//
#include <hip/hip_runtime.h>
#include <hip/hip_bf16.h>
#include <math.h>

typedef _Float16 f16;
typedef _Float16 h8 __attribute__((ext_vector_type(8)));
typedef _Float16 h4 __attribute__((ext_vector_type(4)));
typedef float    f4 __attribute__((ext_vector_type(4)));

__device__ __forceinline__ float elu_f(float v) { return v > 0.f ? v : expm1f(v); }
__device__ __forceinline__ float sigmoid_f(float v) { return 1.f / (1.f + expf(-v)); }

// ================= weight prep: all 8 tensors -> f16 [oc][tap][ic] =================
struct PrepDesc { const float* src; unsigned dstOff; int OC; int IC; int tr; };
struct P8 { PrepDesc d[8]; };

__global__ void prep_weights_k(P8 p, f16* __restrict__ wp) {
    unsigned idx = blockIdx.x * 256u + threadIdx.x;
    for (int s = 0; s < 8; ++s) {
        const int IC = p.d[s].IC, OC = p.d[s].OC;
        const unsigned cnt = (unsigned)(OC * 9 * IC);
        if (idx < cnt) {
            const int oc = idx / (9u * IC);
            const unsigned r = idx - oc * (9u * IC);
            const int tap = r / IC, ic = r - tap * IC;
            const float v = p.d[s].tr ? p.d[s].src[((size_t)ic * OC + oc) * 9 + tap]
                                      : p.d[s].src[((size_t)oc * IC + ic) * 9 + tap];
            wp[p.d[s].dstOff + idx] = (f16)v;
            return;
        }
        idx -= cnt;
    }
}

// ================= enc transpose: [8][512][16][16] f32 -> [8][256px][512] f16 ======
__global__ void enc_transpose_k(const float* __restrict__ enc, f16* __restrict__ out) {
    __shared__ float ts[32][257];
    const int b = blockIdx.x >> 4, cg = blockIdx.x & 15;
    const int tid = threadIdx.x;
    #pragma unroll
    for (int i = 0; i < 32; ++i)
        ts[i][tid] = enc[((size_t)(b * 512 + cg * 32 + i)) * 256 + tid];
    __syncthreads();
    #pragma unroll
    for (int k = 0; k < 4; ++k) {
        h8 v;
        #pragma unroll
        for (int q = 0; q < 8; ++q) v[q] = (f16)ts[k * 8 + q][tid];
        *(h8*)(out + ((size_t)(b * 256 + tid)) * 512 + cg * 32 + k * 8) = v;
    }
}

// ================= split-K finish: sum partials + bias + ELU -> f16 ================
template<int KS, int C>
__launch_bounds__(256)
__global__ void split_finish_k(const float* __restrict__ part, const float* __restrict__ bias,
                               f16* __restrict__ out, int tot) {
    const int i4 = (blockIdx.x * 256 + threadIdx.x) * 4;
    f4 s = *(const f4*)(part + i4);
    #pragma unroll
    for (int k = 1; k < KS; ++k) {
        const f4 v = *(const f4*)(part + (size_t)k * tot + i4);
        s.x += v.x; s.y += v.y; s.z += v.z; s.w += v.w;
    }
    const float4 b4 = *(const float4*)(bias + (i4 & (C - 1)));
    h4 hv = {(f16)elu_f(s.x + b4.x), (f16)elu_f(s.y + b4.y),
             (f16)elu_f(s.z + b4.z), (f16)elu_f(s.w + b4.w)};
    *(h4*)(out + i4) = hv;
}

// ================= Conv2d(k3,p1)+ELU via MFMA, channel-last f16 ====================
// KS>1: write fp32 partials (no bias/ELU) to pout[ks][...]
template<int C, int H, int W, int HT, int WT, int NWN, int KS, bool CF_OUT>
__launch_bounds__(256, 2)
__global__ void conv3_mfma(const f16* __restrict__ in, const f16* __restrict__ wp,
                           const float* __restrict__ bias, f16* __restrict__ out,
                           f16* __restrict__ outcf, float* __restrict__ pout) {
    constexpr int NWR = 4 / NWN;
    constexpr int RH  = HT / NWR;
    constexpr int PIXR = WT + 2;
    constexpr int ROWS = HT + 2;
    constexpr int XB = ROWS * PIXR * 80;
    constexpr int XTILES = W / WT;
    __shared__ __align__(16) char lds[XB + 32 * 592];
    char* xlds = lds;
    char* wlds = lds + XB;

    const int tid = threadIdx.x;
    const int wid = tid >> 6, lane = tid & 63;
    const int ln15 = lane & 15, lg = lane >> 4;
    const int ni = wid % NWN, ri = wid / NWN;
    const int bz = blockIdx.z;
    const int bb = bz / (C / 32), ocg = bz % (C / 32);
    const int oc0 = ocg * 32;
    const int bx = blockIdx.x;
    const int xt = bx % XTILES, ks = bx / XTILES;
    const int h0 = blockIdx.y * HT, w0 = xt * WT;
    const int colb = ni * 16 + ln15;

    f4 acc[RH][2] = {};

    for (int icc = ks * (C / KS); icc < (ks + 1) * (C / KS); icc += 32) {
        __syncthreads();
        for (int t = tid; t < ROWS * PIXR * 4; t += 256) {
            const int g = t & 3, pix = t >> 2;
            const int rr = pix / PIXR, ww = pix - rr * PIXR;
            const int gh = h0 - 1 + rr, gw = w0 - 1 + ww;
            h8 v = {};
            if (gh >= 0 && gh < H && gw >= 0 && gw < W)
                v = *(const h8*)(in + (((size_t)bb * H + gh) * W + gw) * C + icc + g * 8);
            *(h8*)(xlds + pix * 80 + g * 16) = v;
        }
        for (int t = tid; t < 1152; t += 256) {
            const int g = t & 3, s = t >> 2;
            const int o = s / 9, tap = s - o * 9;
            h8 v = *(const h8*)(wp + ((size_t)(oc0 + o) * 9 + tap) * C + icc + g * 8);
            *(h8*)(wlds + o * 592 + tap * 64 + g * 16) = v;
        }
        __syncthreads();

        h8 af[9][2];
        #pragma unroll
        for (int tap = 0; tap < 9; ++tap)
            #pragma unroll
            for (int mt = 0; mt < 2; ++mt)
                af[tap][mt] = *(const h8*)(wlds + (mt * 16 + ln15) * 592 + tap * 64 + lg * 16);

        #pragma unroll
        for (int r = 0; r < RH; ++r) {
            const int orow = ri * RH + r;
            #pragma unroll
            for (int dh = 0; dh < 3; ++dh) {
                #pragma unroll
                for (int dw = 0; dw < 3; ++dw) {
                    const h8 bf = *(const h8*)(xlds + ((orow + dh) * PIXR + colb + dw) * 80 + lg * 16);
                    acc[r][0] = __builtin_amdgcn_mfma_f32_16x16x32_f16(af[dh * 3 + dw][0], bf, acc[r][0], 0, 0, 0);
                    acc[r][1] = __builtin_amdgcn_mfma_f32_16x16x32_f16(af[dh * 3 + dw][1], bf, acc[r][1], 0, 0, 0);
                }
            }
        }
    }

    #pragma unroll
    for (int r = 0; r < RH; ++r) {
        const int oh = h0 + ri * RH + r;
        const int ow = w0 + colb;
        #pragma unroll
        for (int mt = 0; mt < 2; ++mt) {
            const int ocl = mt * 16 + lg * 4;
            const f4 v = acc[r][mt];
            if constexpr (KS > 1) {
                const size_t TOT = (size_t)8 * H * W * C;
                float* pp = pout + (size_t)ks * TOT +
                            (((size_t)bb * H + oh) * W + ow) * C + oc0 + ocl;
                *(f4*)pp = v;
            } else {
                const float4 b4 = *(const float4*)(bias + oc0 + ocl);
                const float e0 = elu_f(v.x + b4.x), e1 = elu_f(v.y + b4.y);
                const float e2 = elu_f(v.z + b4.z), e3 = elu_f(v.w + b4.w);
                if constexpr (CF_OUT) {
                    const size_t n = (size_t)oh * W + ow;
                    const size_t plane = (size_t)H * W;
                    outcf[((size_t)bb * C + oc0 + ocl + 0) * plane + n] = (f16)e0;
                    outcf[((size_t)bb * C + oc0 + ocl + 1) * plane + n] = (f16)e1;
                    outcf[((size_t)bb * C + oc0 + ocl + 2) * plane + n] = (f16)e2;
                    outcf[((size_t)bb * C + oc0 + ocl + 3) * plane + n] = (f16)e3;
                } else {
                    h4 hv = {(f16)e0, (f16)e1, (f16)e2, (f16)e3};
                    *(h4*)(out + (((size_t)bb * H + oh) * W + ow) * C + oc0 + ocl) = hv;
                }
            }
        }
    }
}

// ================= ConvTranspose2d(k3,s2,p1,op1)+ELU via MFMA ======================
template<int IC, int OC, int Hi, int Wi, int KS>
__launch_bounds__(256, 2)
__global__ void convt_mfma(const f16* __restrict__ in, const f16* __restrict__ wp,
                           const float* __restrict__ bias, f16* __restrict__ out,
                           float* __restrict__ pout) {
    constexpr int HT = 4, WT = 16;
    constexpr int PIXR = WT + 1;
    constexpr int ROWS = HT + 1;
    constexpr int XB = ROWS * PIXR * 80;
    constexpr int XTILES = Wi / WT;
    __shared__ __align__(16) char lds[XB + 32 * 592];
    char* xlds = lds;
    char* wlds = lds + XB;

    const int tid = threadIdx.x;
    const int wid = tid >> 6, lane = tid & 63;
    const int ln15 = lane & 15, lg = lane >> 4;
    const int iloc = wid;
    const int bz = blockIdx.z;
    const int bb = bz / (OC / 32), ocg = bz % (OC / 32);
    const int oc0 = ocg * 32;
    const int bx = blockIdx.x;
    const int xt = bx % XTILES, ks = bx / XTILES;
    const int i0 = blockIdx.y * HT, j0 = xt * WT;

    f4 acc[4][2] = {};

    for (int icc = ks * (IC / KS); icc < (ks + 1) * (IC / KS); icc += 32) {
        __syncthreads();
        for (int t = tid; t < ROWS * PIXR * 4; t += 256) {
            const int g = t & 3, pix = t >> 2;
            const int rr = pix / PIXR, ww = pix - rr * PIXR;
            const int gh = i0 + rr, gw = j0 + ww;
            h8 v = {};
            if (gh < Hi && gw < Wi)
                v = *(const h8*)(in + (((size_t)bb * Hi + gh) * Wi + gw) * IC + icc + g * 8);
            *(h8*)(xlds + pix * 80 + g * 16) = v;
        }
        for (int t = tid; t < 1152; t += 256) {
            const int g = t & 3, s = t >> 2;
            const int o = s / 9, tap = s - o * 9;
            h8 v = *(const h8*)(wp + ((size_t)(oc0 + o) * 9 + tap) * IC + icc + g * 8);
            *(h8*)(wlds + o * 592 + tap * 64 + g * 16) = v;
        }
        __syncthreads();

        h8 af[9][2];
        #pragma unroll
        for (int tap = 0; tap < 9; ++tap)
            #pragma unroll
            for (int mt = 0; mt < 2; ++mt)
                af[tap][mt] = *(const h8*)(wlds + (mt * 16 + ln15) * 592 + tap * 64 + lg * 16);

        h8 bf[2][2];
        #pragma unroll
        for (int a = 0; a < 2; ++a)
            #pragma unroll
            for (int b = 0; b < 2; ++b)
                bf[a][b] = *(const h8*)(xlds + ((iloc + a) * PIXR + ln15 + b) * 80 + lg * 16);

        #pragma unroll
        for (int p = 0; p < 4; ++p) {
            const int di = p >> 1, dj = p & 1;
            #pragma unroll
            for (int a = 0; a < 2; ++a) {
                if (a > di) continue;
                const int kh = 1 + di - 2 * a;
                #pragma unroll
                for (int b = 0; b < 2; ++b) {
                    if (b > dj) continue;
                    const int kw = 1 + dj - 2 * b;
                    const int tap = kh * 3 + kw;
                    acc[p][0] = __builtin_amdgcn_mfma_f32_16x16x32_f16(af[tap][0], bf[a][b], acc[p][0], 0, 0, 0);
                    acc[p][1] = __builtin_amdgcn_mfma_f32_16x16x32_f16(af[tap][1], bf[a][b], acc[p][1], 0, 0, 0);
                }
            }
        }
    }

    #pragma unroll
    for (int p = 0; p < 4; ++p) {
        const int orow = 2 * (i0 + iloc) + (p >> 1);
        const int ocol = 2 * (j0 + ln15) + (p & 1);
        #pragma unroll
        for (int mt = 0; mt < 2; ++mt) {
            const int ocl = mt * 16 + lg * 4;
            const f4 v = acc[p][mt];
            if constexpr (KS > 1) {
                const size_t TOT = (size_t)8 * (2 * Hi) * (2 * Wi) * OC;
                float* pp = pout + (size_t)ks * TOT +
                            (((size_t)bb * (2 * Hi) + orow) * (2 * Wi) + ocol) * OC + oc0 + ocl;
                *(f4*)pp = v;
            } else {
                const float4 b4 = *(const float4*)(bias + oc0 + ocl);
                h4 hv = {(f16)elu_f(v.x + b4.x), (f16)elu_f(v.y + b4.y),
                         (f16)elu_f(v.z + b4.z), (f16)elu_f(v.w + b4.w)};
                *(h4*)(out + (((size_t)bb * (2 * Hi) + orow) * (2 * Wi) + ocol) * OC + oc0 + ocl) = hv;
            }
        }
    }
}

// ================= Gram via MFMA, LDS-free fragments ===============================
#define KCH 128
__launch_bounds__(256)
__global__ void gram_mfma_k(const f16* __restrict__ x3, const float* __restrict__ sem,
                            float* __restrict__ part, float* __restrict__ sums) {
    __shared__ float pl[4][1024];
    __shared__ float sl[4][64];
    const int b = blockIdx.y, kc = blockIdx.x;
    const int tid = threadIdx.x, wid = tid >> 6, lane = tid & 63;
    const int row = lane & 15, kg = lane >> 4;
    const size_t N = 65536;
    const int k0 = kc * (65536 / KCH) + wid * (65536 / KCH / 4);

    const f16*   xa = x3  + ((size_t)b * 32 + row) * N + k0 + kg * 8;
    const float* sb = sem + ((size_t)b * 32 + row) * N + k0 + kg * 8;

    f4 acc00 = {}, acc01 = {}, acc10 = {}, acc11 = {};
    float sx0 = 0.f, sx1 = 0.f, ss0 = 0.f, ss1 = 0.f;

    #pragma unroll
    for (int s = 0; s < 4; ++s) {
        const int ko = s * 32;
        const h8 a0 = *(const h8*)(xa + ko);
        const h8 a1 = *(const h8*)(xa + 16 * N + ko);
        const float4 f0 = *(const float4*)(sb + ko);
        const float4 f1 = *(const float4*)(sb + ko + 4);
        const float4 g0 = *(const float4*)(sb + 16 * N + ko);
        const float4 g1 = *(const float4*)(sb + 16 * N + ko + 4);
        const h8 b0 = {(f16)f0.x, (f16)f0.y, (f16)f0.z, (f16)f0.w,
                       (f16)f1.x, (f16)f1.y, (f16)f1.z, (f16)f1.w};
        const h8 b1 = {(f16)g0.x, (f16)g0.y, (f16)g0.z, (f16)g0.w,
                       (f16)g1.x, (f16)g1.y, (f16)g1.z, (f16)g1.w};
        acc00 = __builtin_amdgcn_mfma_f32_16x16x32_f16(a0, b0, acc00, 0, 0, 0);
        acc01 = __builtin_amdgcn_mfma_f32_16x16x32_f16(a0, b1, acc01, 0, 0, 0);
        acc10 = __builtin_amdgcn_mfma_f32_16x16x32_f16(a1, b0, acc10, 0, 0, 0);
        acc11 = __builtin_amdgcn_mfma_f32_16x16x32_f16(a1, b1, acc11, 0, 0, 0);
        #pragma unroll
        for (int q = 0; q < 8; ++q) { sx0 += (float)a0[q]; sx1 += (float)a1[q]; }
        ss0 += (f0.x + f0.y + f0.z + f0.w) + (f1.x + f1.y + f1.z + f1.w);
        ss1 += (g0.x + g0.y + g0.z + g0.w) + (g1.x + g1.y + g1.z + g1.w);
    }

    sx0 += __shfl_xor(sx0, 16); sx0 += __shfl_xor(sx0, 32);
    sx1 += __shfl_xor(sx1, 16); sx1 += __shfl_xor(sx1, 32);
    ss0 += __shfl_xor(ss0, 16); ss0 += __shfl_xor(ss0, 32);
    ss1 += __shfl_xor(ss1, 16); ss1 += __shfl_xor(ss1, 32);

    #pragma unroll
    for (int reg = 0; reg < 4; ++reg) {
        const int c0 = 4 * kg + reg;
        pl[wid][c0 * 32 + row]               = acc00[reg];
        pl[wid][c0 * 32 + 16 + row]          = acc01[reg];
        pl[wid][(16 + c0) * 32 + row]        = acc10[reg];
        pl[wid][(16 + c0) * 32 + 16 + row]   = acc11[reg];
    }
    if (lane < 16) {
        sl[wid][row]      = sx0;
        sl[wid][16 + row] = sx1;
        sl[wid][32 + row] = ss0;
        sl[wid][48 + row] = ss1;
    }
    __syncthreads();

    float* pb = part + ((size_t)b * KCH + kc) * 1024;
    #pragma unroll
    for (int t = tid; t < 1024; t += 256)
        pb[t] = pl[0][t] + pl[1][t] + pl[2][t] + pl[3][t];
    if (tid < 64)
        sums[((size_t)b * KCH + kc) * 64 + tid] = sl[0][tid] + sl[1][tid] + sl[2][tid] + sl[3][tid];
}

// ================= per-batch: reduce -> softmax(Wa G Wa^T + bias) -> u, cb =========
__launch_bounds__(256)
__global__ void attn_finish_v3(const float* __restrict__ part, const float* __restrict__ sums,
                               const float* __restrict__ wa, const float* __restrict__ ba,
                               const float* __restrict__ wf, const float* __restrict__ bf,
                               float* __restrict__ u, float* __restrict__ cb) {
    __shared__ float G[32][33];
    __shared__ float T[16][33];
    __shared__ float A[16][17];
    __shared__ float Sx[32], Ss[32], px[16], ps[16], v[16];
    const int b = blockIdx.x, tid = threadIdx.x;

    float a4[4] = {0.f, 0.f, 0.f, 0.f};
    for (int p = 0; p < KCH; ++p) {
        const float* pp = part + ((size_t)b * KCH + p) * 1024 + tid;
        a4[0] += pp[0]; a4[1] += pp[256]; a4[2] += pp[512]; a4[3] += pp[768];
    }
    #pragma unroll
    for (int q = 0; q < 4; ++q) {
        const int t = tid + q * 256;
        G[t >> 5][t & 31] = a4[q];
    }
    if (tid < 64) {
        float s = 0.f;
        for (int p = 0; p < KCH; ++p) s += sums[((size_t)b * KCH + p) * 64 + tid];
        if (tid < 32) Sx[tid] = s; else Ss[tid - 32] = s;
    }
    __syncthreads();
    for (int t = tid; t < 512; t += 256) {
        const int c = t >> 5, f = t & 31;
        float s = 0.f;
        #pragma unroll
        for (int e = 0; e < 32; ++e) s = fmaf(wa[c * 32 + e], G[e][f], s);
        T[c][f] = s;
    }
    if (tid < 32) {
        const int c = tid & 15;
        const float* S = (tid < 16) ? Sx : Ss;
        float s = 0.f;
        #pragma unroll
        for (int e = 0; e < 32; ++e) s = fmaf(wa[c * 32 + e], S[e], s);
        if (tid < 16) px[c] = s; else ps[c] = s;
    }
    __syncthreads();
    {
        const int c = tid >> 4, d = tid & 15;
        float s = 0.f;
        #pragma unroll
        for (int f2 = 0; f2 < 32; ++f2) s = fmaf(T[c][f2], wa[d * 32 + f2], s);
        s += px[c] * ba[d] + ba[c] * ps[d] + 65536.f * ba[c] * ba[d];
        A[c][d] = s;
    }
    __syncthreads();
    if (tid < 16) {
        float m = A[tid][0];
        #pragma unroll
        for (int d = 1; d < 16; ++d) m = fmaxf(m, A[tid][d]);
        float s = 0.f;
        #pragma unroll
        for (int d = 0; d < 16; ++d) { const float e = expf(A[tid][d] - m); A[tid][d] = e; s += e; }
        const float inv = 1.f / s;
        #pragma unroll
        for (int d = 0; d < 16; ++d) A[tid][d] *= inv;
    }
    __syncthreads();
    if (tid < 16) {
        float s = wf[tid];
        #pragma unroll
        for (int c = 0; c < 16; ++c) s = fmaf(wf[c], A[c][tid], s);
        v[tid] = s;
    }
    __syncthreads();
    if (tid < 32) {
        float s = 0.f;
        #pragma unroll
        for (int d = 0; d < 16; ++d) s = fmaf(v[d], wa[d * 32 + tid], s);
        u[b * 32 + tid] = s;
    }
    if (tid == 0) {
        float s2 = bf[0];
        #pragma unroll
        for (int d = 0; d < 16; ++d) s2 = fmaf(v[d], ba[d], s2);
        cb[b] = s2;
    }
}

// ================= final: out[b][n] = sigmoid(cb + sum_e u[e]*x3cf[e][n]) ==========
__launch_bounds__(256)
__global__ void final_k(const f16* __restrict__ x3, const float* __restrict__ u,
                        const float* __restrict__ cb, float* __restrict__ out) {
    const int b = blockIdx.y;
    const int nn = blockIdx.x * 256 + threadIdx.x;
    const size_t N = 65536;
    const f16* xb = x3 + (size_t)b * 32 * N + nn;
    float acc = cb[b];
    #pragma unroll
    for (int e = 0; e < 32; ++e) acc = fmaf(u[b * 32 + e], (float)xb[(size_t)e * N], acc);
    out[(size_t)b * N + nn] = sigmoid_f(acc);
}

extern "C" void kernel_launch(void* const* d_in, const int* in_sizes, int n_in,
                              void* d_out, int out_size, void* d_ws, size_t ws_size,
                              hipStream_t stream) {
    const float* enc   = (const float*)d_in[0];
    const float* sem   = (const float*)d_in[1];
    const float* wt0   = (const float*)d_in[2];
    const float* bt0   = (const float*)d_in[3];
    const float* wc0   = (const float*)d_in[4];
    const float* bc0   = (const float*)d_in[5];
    const float* wt1   = (const float*)d_in[6];
    const float* bt1   = (const float*)d_in[7];
    const float* wc1   = (const float*)d_in[8];
    const float* bc1   = (const float*)d_in[9];
    const float* wt2   = (const float*)d_in[10];
    const float* bt2   = (const float*)d_in[11];
    const float* wc2   = (const float*)d_in[12];
    const float* bc2   = (const float*)d_in[13];
    const float* wt3   = (const float*)d_in[14];
    const float* bt3   = (const float*)d_in[15];
    const float* wc3   = (const float*)d_in[16];
    const float* bc3   = (const float*)d_in[17];
    const float* wattn = (const float*)d_in[18];
    const float* battn = (const float*)d_in[19];
    const float* wfin  = (const float*)d_in[20];
    const float* bfin  = (const float*)d_in[21];

    char* W = (char*)d_ws;
    f16*   actA   = (f16*)(W + 0);            // 32 MB
    f16*   actB   = (f16*)(W + 33554432);     // 32 MB
    f16*   x3cf   = (f16*)(W + 67108864);     // 32 MB: split-K partials early, x3 channel-first late
    float* pf     = (float*)(W + 67108864);   // alias of x3cf region (fp32 partials)
    f16*   wp     = (f16*)(W + 100663296);    // 4.7 MB
    f16*   enc_cl = (f16*)(W + 105906176);    // 2 MB
    float* part   = (float*)(W + 108003328);  // 4 MB
    float* sums   = (float*)(W + 112197632);  // 256 KB
    float* u      = (float*)(W + 112459776);
    float* cb     = (float*)(W + 112460800);
    float* out    = (float*)d_out;

    P8 p;
    p.d[0] = {wt0, 0u,       256, 512, 1};
    p.d[1] = {wc0, 1179648u, 256, 256, 0};
    p.d[2] = {wt1, 1769472u, 128, 256, 1};
    p.d[3] = {wc1, 2064384u, 128, 128, 0};
    p.d[4] = {wt2, 2211840u,  64, 128, 1};
    p.d[5] = {wc2, 2285568u,  64,  64, 0};
    p.d[6] = {wt3, 2322432u,  32,  64, 1};
    p.d[7] = {wc3, 2340864u,  32,  32, 0};
    prep_weights_k<<<9180, 256, 0, stream>>>(p, wp);
    enc_transpose_k<<<128, 256, 0, stream>>>(enc, enc_cl);

    // L0: convT 512->256, 16x16 -> 32x32, split-K=4 (1024 blocks)
    convt_mfma<512, 256, 16, 16, 4><<<dim3(4, 4, 64), 256, 0, stream>>>(enc_cl, wp, nullptr, nullptr, pf);
    split_finish_k<4, 256><<<2048, 256, 0, stream>>>(pf, bt0, actA, 2097152);
    // L1: conv3 256ch, 32x32, split-K=4 (1024 blocks)
    conv3_mfma<256, 32, 32, 8, 32, 2, 4, false><<<dim3(4, 4, 64), 256, 0, stream>>>(actA, wp + 1179648, nullptr, nullptr, nullptr, pf);
    split_finish_k<4, 256><<<2048, 256, 0, stream>>>(pf, bc0, actB, 2097152);
    // L2: convT 256->128, 32x32 -> 64x64, split-K=2 (1024 blocks)
    convt_mfma<256, 128, 32, 32, 2><<<dim3(4, 8, 32), 256, 0, stream>>>(actB, wp + 1769472, nullptr, nullptr, pf);
    split_finish_k<2, 128><<<4096, 256, 0, stream>>>(pf, bt1, actA, 4194304);
    // L3: conv3 128ch, 64x64, split-K=2 (1024 blocks)
    conv3_mfma<128, 64, 64, 4, 64, 4, 2, false><<<dim3(2, 16, 32), 256, 0, stream>>>(actA, wp + 2064384, nullptr, nullptr, nullptr, pf);
    split_finish_k<2, 128><<<4096, 256, 0, stream>>>(pf, bc1, actB, 4194304);
    // L4-L7: direct (grids >= 1024 blocks)
    convt_mfma<128, 64, 64, 64, 1>     <<<dim3(4, 16, 16), 256, 0, stream>>>(actB, wp + 2211840, bt2, actA, nullptr);
    conv3_mfma<64, 128, 128, 4, 64, 4, 1, false><<<dim3(2, 32, 16), 256, 0, stream>>>(actA, wp + 2285568, bc2, actB, nullptr, nullptr);
    convt_mfma<64, 32, 128, 128, 1>    <<<dim3(8, 32, 8),  256, 0, stream>>>(actB, wp + 2322432, bt3, actA, nullptr);
    conv3_mfma<32, 256, 256, 4, 64, 4, 1, true><<<dim3(4, 64, 8), 256, 0, stream>>>(actA, wp + 2340864, bc3, nullptr, x3cf, nullptr);

    gram_mfma_k<<<dim3(KCH, 8), 256, 0, stream>>>(x3cf, sem, part, sums);
    attn_finish_v3<<<8, 256, 0, stream>>>(part, sums, wattn, battn, wfin, bfin, u, cb);
    final_k<<<dim3(256, 8), 256, 0, stream>>>(x3cf, u, cb, out);
}

// Round 6
// 280.059 us; speedup vs baseline: 14.8054x; 1.0350x over previous
//
#include <hip/hip_runtime.h>
#include <hip/hip_bf16.h>
#include <math.h>

typedef _Float16 f16;
typedef _Float16 h8 __attribute__((ext_vector_type(8)));
typedef _Float16 h4 __attribute__((ext_vector_type(4)));
typedef float    f4 __attribute__((ext_vector_type(4)));

__device__ __forceinline__ float elu_f(float v) { return v > 0.f ? v : expm1f(v); }
__device__ __forceinline__ float sigmoid_f(float v) { return 1.f / (1.f + expf(-v)); }

// ================= weight prep: all 8 tensors -> f16 [oc][tap][ic] =================
struct PrepDesc { const float* src; unsigned dstOff; int OC; int IC; int tr; };
struct P8 { PrepDesc d[8]; };

__global__ void prep_weights_k(P8 p, f16* __restrict__ wp) {
    unsigned idx = blockIdx.x * 256u + threadIdx.x;
    for (int s = 0; s < 8; ++s) {
        const int IC = p.d[s].IC, OC = p.d[s].OC;
        const unsigned cnt = (unsigned)(OC * 9 * IC);
        if (idx < cnt) {
            const int oc = idx / (9u * IC);
            const unsigned r = idx - oc * (9u * IC);
            const int tap = r / IC, ic = r - tap * IC;
            const float v = p.d[s].tr ? p.d[s].src[((size_t)ic * OC + oc) * 9 + tap]
                                      : p.d[s].src[((size_t)oc * IC + ic) * 9 + tap];
            wp[p.d[s].dstOff + idx] = (f16)v;
            return;
        }
        idx -= cnt;
    }
}

// ================= enc transpose: [8][512][16][16] f32 -> [8][256px][512] f16 ======
__global__ void enc_transpose_k(const float* __restrict__ enc, f16* __restrict__ out) {
    __shared__ float ts[32][257];
    const int b = blockIdx.x >> 4, cg = blockIdx.x & 15;
    const int tid = threadIdx.x;
    #pragma unroll
    for (int i = 0; i < 32; ++i)
        ts[i][tid] = enc[((size_t)(b * 512 + cg * 32 + i)) * 256 + tid];
    __syncthreads();
    #pragma unroll
    for (int k = 0; k < 4; ++k) {
        h8 v;
        #pragma unroll
        for (int q = 0; q < 8; ++q) v[q] = (f16)ts[k * 8 + q][tid];
        *(h8*)(out + ((size_t)(b * 256 + tid)) * 512 + cg * 32 + k * 8) = v;
    }
}

// ================= split-K finish: sum partials + bias + ELU -> f16 ================
template<int KS, int C>
__launch_bounds__(256)
__global__ void split_finish_k(const float* __restrict__ part, const float* __restrict__ bias,
                               f16* __restrict__ out, int tot) {
    const int i4 = (blockIdx.x * 256 + threadIdx.x) * 4;
    f4 s = *(const f4*)(part + i4);
    #pragma unroll
    for (int k = 1; k < KS; ++k) {
        const f4 v = *(const f4*)(part + (size_t)k * tot + i4);
        s.x += v.x; s.y += v.y; s.z += v.z; s.w += v.w;
    }
    const float4 b4 = *(const float4*)(bias + (i4 & (C - 1)));
    h4 hv = {(f16)elu_f(s.x + b4.x), (f16)elu_f(s.y + b4.y),
             (f16)elu_f(s.z + b4.z), (f16)elu_f(s.w + b4.w)};
    *(h4*)(out + i4) = hv;
}

// ================= Conv2d(k3,p1)+ELU via MFMA, channel-last f16 ====================
template<int C, int H, int W, int HT, int WT, int NWN, int KS>
__launch_bounds__(256, 2)
__global__ void conv3_mfma(const f16* __restrict__ in, const f16* __restrict__ wp,
                           const float* __restrict__ bias, f16* __restrict__ out,
                           float* __restrict__ pout) {
    constexpr int NWR = 4 / NWN;
    constexpr int RH  = HT / NWR;
    constexpr int PIXR = WT + 2;
    constexpr int ROWS = HT + 2;
    constexpr int XB = ROWS * PIXR * 80;
    constexpr int XTILES = W / WT;
    __shared__ __align__(16) char lds[XB + 32 * 592];
    char* xlds = lds;
    char* wlds = lds + XB;

    const int tid = threadIdx.x;
    const int wid = tid >> 6, lane = tid & 63;
    const int ln15 = lane & 15, lg = lane >> 4;
    const int ni = wid % NWN, ri = wid / NWN;
    const int bz = blockIdx.z;
    const int bb = bz / (C / 32), ocg = bz % (C / 32);
    const int oc0 = ocg * 32;
    const int bx = blockIdx.x;
    const int xt = bx % XTILES, ks = bx / XTILES;
    const int h0 = blockIdx.y * HT, w0 = xt * WT;
    const int colb = ni * 16 + ln15;

    f4 acc[RH][2] = {};

    for (int icc = ks * (C / KS); icc < (ks + 1) * (C / KS); icc += 32) {
        __syncthreads();
        for (int t = tid; t < ROWS * PIXR * 4; t += 256) {
            const int g = t & 3, pix = t >> 2;
            const int rr = pix / PIXR, ww = pix - rr * PIXR;
            const int gh = h0 - 1 + rr, gw = w0 - 1 + ww;
            h8 v = {};
            if (gh >= 0 && gh < H && gw >= 0 && gw < W)
                v = *(const h8*)(in + (((size_t)bb * H + gh) * W + gw) * C + icc + g * 8);
            *(h8*)(xlds + pix * 80 + g * 16) = v;
        }
        for (int t = tid; t < 1152; t += 256) {
            const int g = t & 3, s = t >> 2;
            const int o = s / 9, tap = s - o * 9;
            h8 v = *(const h8*)(wp + ((size_t)(oc0 + o) * 9 + tap) * C + icc + g * 8);
            *(h8*)(wlds + o * 592 + tap * 64 + g * 16) = v;
        }
        __syncthreads();

        h8 af[9][2];
        #pragma unroll
        for (int tap = 0; tap < 9; ++tap)
            #pragma unroll
            for (int mt = 0; mt < 2; ++mt)
                af[tap][mt] = *(const h8*)(wlds + (mt * 16 + ln15) * 592 + tap * 64 + lg * 16);

        #pragma unroll
        for (int r = 0; r < RH; ++r) {
            const int orow = ri * RH + r;
            #pragma unroll
            for (int dh = 0; dh < 3; ++dh) {
                #pragma unroll
                for (int dw = 0; dw < 3; ++dw) {
                    const h8 bf = *(const h8*)(xlds + ((orow + dh) * PIXR + colb + dw) * 80 + lg * 16);
                    acc[r][0] = __builtin_amdgcn_mfma_f32_16x16x32_f16(af[dh * 3 + dw][0], bf, acc[r][0], 0, 0, 0);
                    acc[r][1] = __builtin_amdgcn_mfma_f32_16x16x32_f16(af[dh * 3 + dw][1], bf, acc[r][1], 0, 0, 0);
                }
            }
        }
    }

    #pragma unroll
    for (int r = 0; r < RH; ++r) {
        const int oh = h0 + ri * RH + r;
        const int ow = w0 + colb;
        #pragma unroll
        for (int mt = 0; mt < 2; ++mt) {
            const int ocl = mt * 16 + lg * 4;
            const f4 v = acc[r][mt];
            if constexpr (KS > 1) {
                const size_t TOT = (size_t)8 * H * W * C;
                float* pp = pout + (size_t)ks * TOT +
                            (((size_t)bb * H + oh) * W + ow) * C + oc0 + ocl;
                *(f4*)pp = v;
            } else {
                const float4 b4 = *(const float4*)(bias + oc0 + ocl);
                h4 hv = {(f16)elu_f(v.x + b4.x), (f16)elu_f(v.y + b4.y),
                         (f16)elu_f(v.z + b4.z), (f16)elu_f(v.w + b4.w)};
                *(h4*)(out + (((size_t)bb * H + oh) * W + ow) * C + oc0 + ocl) = hv;
            }
        }
    }
}

// ================= ConvTranspose2d(k3,s2,p1,op1)+ELU via MFMA ======================
template<int IC, int OC, int Hi, int Wi, int KS>
__launch_bounds__(256, 2)
__global__ void convt_mfma(const f16* __restrict__ in, const f16* __restrict__ wp,
                           const float* __restrict__ bias, f16* __restrict__ out,
                           float* __restrict__ pout) {
    constexpr int HT = 4, WT = 16;
    constexpr int PIXR = WT + 1;
    constexpr int ROWS = HT + 1;
    constexpr int XB = ROWS * PIXR * 80;
    constexpr int XTILES = Wi / WT;
    __shared__ __align__(16) char lds[XB + 32 * 592];
    char* xlds = lds;
    char* wlds = lds + XB;

    const int tid = threadIdx.x;
    const int wid = tid >> 6, lane = tid & 63;
    const int ln15 = lane & 15, lg = lane >> 4;
    const int iloc = wid;
    const int bz = blockIdx.z;
    const int bb = bz / (OC / 32), ocg = bz % (OC / 32);
    const int oc0 = ocg * 32;
    const int bx = blockIdx.x;
    const int xt = bx % XTILES, ks = bx / XTILES;
    const int i0 = blockIdx.y * HT, j0 = xt * WT;

    f4 acc[4][2] = {};

    for (int icc = ks * (IC / KS); icc < (ks + 1) * (IC / KS); icc += 32) {
        __syncthreads();
        for (int t = tid; t < ROWS * PIXR * 4; t += 256) {
            const int g = t & 3, pix = t >> 2;
            const int rr = pix / PIXR, ww = pix - rr * PIXR;
            const int gh = i0 + rr, gw = j0 + ww;
            h8 v = {};
            if (gh < Hi && gw < Wi)
                v = *(const h8*)(in + (((size_t)bb * Hi + gh) * Wi + gw) * IC + icc + g * 8);
            *(h8*)(xlds + pix * 80 + g * 16) = v;
        }
        for (int t = tid; t < 1152; t += 256) {
            const int g = t & 3, s = t >> 2;
            const int o = s / 9, tap = s - o * 9;
            h8 v = *(const h8*)(wp + ((size_t)(oc0 + o) * 9 + tap) * IC + icc + g * 8);
            *(h8*)(wlds + o * 592 + tap * 64 + g * 16) = v;
        }
        __syncthreads();

        h8 af[9][2];
        #pragma unroll
        for (int tap = 0; tap < 9; ++tap)
            #pragma unroll
            for (int mt = 0; mt < 2; ++mt)
                af[tap][mt] = *(const h8*)(wlds + (mt * 16 + ln15) * 592 + tap * 64 + lg * 16);

        h8 bf[2][2];
        #pragma unroll
        for (int a = 0; a < 2; ++a)
            #pragma unroll
            for (int b = 0; b < 2; ++b)
                bf[a][b] = *(const h8*)(xlds + ((iloc + a) * PIXR + ln15 + b) * 80 + lg * 16);

        #pragma unroll
        for (int p = 0; p < 4; ++p) {
            const int di = p >> 1, dj = p & 1;
            #pragma unroll
            for (int a = 0; a < 2; ++a) {
                if (a > di) continue;
                const int kh = 1 + di - 2 * a;
                #pragma unroll
                for (int b = 0; b < 2; ++b) {
                    if (b > dj) continue;
                    const int kw = 1 + dj - 2 * b;
                    const int tap = kh * 3 + kw;
                    acc[p][0] = __builtin_amdgcn_mfma_f32_16x16x32_f16(af[tap][0], bf[a][b], acc[p][0], 0, 0, 0);
                    acc[p][1] = __builtin_amdgcn_mfma_f32_16x16x32_f16(af[tap][1], bf[a][b], acc[p][1], 0, 0, 0);
                }
            }
        }
    }

    #pragma unroll
    for (int p = 0; p < 4; ++p) {
        const int orow = 2 * (i0 + iloc) + (p >> 1);
        const int ocol = 2 * (j0 + ln15) + (p & 1);
        #pragma unroll
        for (int mt = 0; mt < 2; ++mt) {
            const int ocl = mt * 16 + lg * 4;
            const f4 v = acc[p][mt];
            if constexpr (KS > 1) {
                const size_t TOT = (size_t)8 * (2 * Hi) * (2 * Wi) * OC;
                float* pp = pout + (size_t)ks * TOT +
                            (((size_t)bb * (2 * Hi) + orow) * (2 * Wi) + ocol) * OC + oc0 + ocl;
                *(f4*)pp = v;
            } else {
                const float4 b4 = *(const float4*)(bias + oc0 + ocl);
                h4 hv = {(f16)elu_f(v.x + b4.x), (f16)elu_f(v.y + b4.y),
                         (f16)elu_f(v.z + b4.z), (f16)elu_f(v.w + b4.w)};
                *(h4*)(out + (((size_t)bb * (2 * Hi) + orow) * (2 * Wi) + ocol) * OC + oc0 + ocl) = hv;
            }
        }
    }
}

// ================= Gram via MFMA: x3 channel-LAST, per-wave LDS transpose ==========
// x3cl f16 [8][65536][32], sem f32 [8][32][65536]
// part[b][128][1024] (c*32+d), sums[b][128][64]
#define KCH 128
__launch_bounds__(256)
__global__ void gram_mfma_k(const f16* __restrict__ x3, const float* __restrict__ sem,
                            float* __restrict__ part, float* __restrict__ sums) {
    __shared__ __align__(16) f16 xs[4][32][66];   // [wave][px][ch], 66-stride -> 2-way banks
    __shared__ float pl[4][1024];
    __shared__ float sl[4][64];
    const int b = blockIdx.y, kc = blockIdx.x;
    const int tid = threadIdx.x, wid = tid >> 6, lane = tid & 63;
    const int row = lane & 15, kg = lane >> 4;
    const size_t N = 65536;
    const int p0 = kc * 512 + wid * 128;          // wave's 128 pixels

    const float* sb = sem + ((size_t)b * 32 + row) * N + p0 + kg * 8;
    const int spx = lane >> 1, shalf = lane & 1;  // staging role: px, channel-half

    f4 acc00 = {}, acc01 = {}, acc10 = {}, acc11 = {};
    float sx0 = 0.f, sx1 = 0.f, ss0 = 0.f, ss1 = 0.f;

    for (int s = 0; s < 4; ++s) {
        const f16* xp = x3 + ((size_t)b * N + p0 + s * 32 + spx) * 32 + shalf * 16;
        const h8 w0 = *(const h8*)xp;
        const h8 w1 = *(const h8*)(xp + 8);
        const float4 f0 = *(const float4*)(sb + s * 32);
        const float4 f1 = *(const float4*)(sb + s * 32 + 4);
        const float4 g0 = *(const float4*)(sb + 16 * N + s * 32);
        const float4 g1 = *(const float4*)(sb + 16 * N + s * 32 + 4);
        __syncthreads();                           // prior reads of xs complete
        *(h8*)&xs[wid][spx][shalf * 16]     = w0;
        *(h8*)&xs[wid][spx][shalf * 16 + 8] = w1;
        __syncthreads();                           // writes visible
        h8 a0, a1;
        #pragma unroll
        for (int j = 0; j < 8; ++j) {
            a0[j] = xs[wid][kg * 8 + j][row];
            a1[j] = xs[wid][kg * 8 + j][row + 16];
        }
        const h8 b0 = {(f16)f0.x, (f16)f0.y, (f16)f0.z, (f16)f0.w,
                       (f16)f1.x, (f16)f1.y, (f16)f1.z, (f16)f1.w};
        const h8 b1 = {(f16)g0.x, (f16)g0.y, (f16)g0.z, (f16)g0.w,
                       (f16)g1.x, (f16)g1.y, (f16)g1.z, (f16)g1.w};
        acc00 = __builtin_amdgcn_mfma_f32_16x16x32_f16(a0, b0, acc00, 0, 0, 0);
        acc01 = __builtin_amdgcn_mfma_f32_16x16x32_f16(a0, b1, acc01, 0, 0, 0);
        acc10 = __builtin_amdgcn_mfma_f32_16x16x32_f16(a1, b0, acc10, 0, 0, 0);
        acc11 = __builtin_amdgcn_mfma_f32_16x16x32_f16(a1, b1, acc11, 0, 0, 0);
        #pragma unroll
        for (int q = 0; q < 8; ++q) { sx0 += (float)a0[q]; sx1 += (float)a1[q]; }
        ss0 += (f0.x + f0.y + f0.z + f0.w) + (f1.x + f1.y + f1.z + f1.w);
        ss1 += (g0.x + g0.y + g0.z + g0.w) + (g1.x + g1.y + g1.z + g1.w);
    }

    // reduce channel sums across kg groups (lanes sharing `row`)
    sx0 += __shfl_xor(sx0, 16); sx0 += __shfl_xor(sx0, 32);
    sx1 += __shfl_xor(sx1, 16); sx1 += __shfl_xor(sx1, 32);
    ss0 += __shfl_xor(ss0, 16); ss0 += __shfl_xor(ss0, 32);
    ss1 += __shfl_xor(ss1, 16); ss1 += __shfl_xor(ss1, 32);

    #pragma unroll
    for (int reg = 0; reg < 4; ++reg) {
        const int c0 = 4 * kg + reg;
        pl[wid][c0 * 32 + row]               = acc00[reg];
        pl[wid][c0 * 32 + 16 + row]          = acc01[reg];
        pl[wid][(16 + c0) * 32 + row]        = acc10[reg];
        pl[wid][(16 + c0) * 32 + 16 + row]   = acc11[reg];
    }
    if (lane < 16) {
        sl[wid][row]      = sx0;
        sl[wid][16 + row] = sx1;
        sl[wid][32 + row] = ss0;
        sl[wid][48 + row] = ss1;
    }
    __syncthreads();

    float* pb = part + ((size_t)b * KCH + kc) * 1024;
    #pragma unroll
    for (int t = tid; t < 1024; t += 256)
        pb[t] = pl[0][t] + pl[1][t] + pl[2][t] + pl[3][t];
    if (tid < 64)
        sums[((size_t)b * KCH + kc) * 64 + tid] = sl[0][tid] + sl[1][tid] + sl[2][tid] + sl[3][tid];
}

// ================= two-level reduce: 128 partials -> 8 ============================
__launch_bounds__(256)
__global__ void gram_reduce_k(const float* __restrict__ part, const float* __restrict__ sums,
                              float* __restrict__ part2, float* __restrict__ sums2) {
    const int b = blockIdx.y, g = blockIdx.x;     // 8 x 8
    const int tid = threadIdx.x;
    const int i4 = tid * 4;
    f4 a = {};
    #pragma unroll 4
    for (int ch = 0; ch < 16; ++ch) {
        const f4 v = *(const f4*)(part + ((size_t)b * KCH + g * 16 + ch) * 1024 + i4);
        a.x += v.x; a.y += v.y; a.z += v.z; a.w += v.w;
    }
    *(f4*)(part2 + ((size_t)b * 8 + g) * 1024 + i4) = a;
    if (tid < 64) {
        float s = 0.f;
        #pragma unroll 4
        for (int ch = 0; ch < 16; ++ch) s += sums[((size_t)b * KCH + g * 16 + ch) * 64 + tid];
        sums2[((size_t)b * 8 + g) * 64 + tid] = s;
    }
}

// ================= per-batch: reduce -> softmax(Wa G Wa^T + bias) -> u, cb =========
__launch_bounds__(256)
__global__ void attn_finish_v3(const float* __restrict__ part, const float* __restrict__ sums,
                               const float* __restrict__ wa, const float* __restrict__ ba,
                               const float* __restrict__ wf, const float* __restrict__ bf,
                               float* __restrict__ u, float* __restrict__ cb) {
    __shared__ float G[32][33];
    __shared__ float T[16][33];
    __shared__ float A[16][17];
    __shared__ float Sx[32], Ss[32], px[16], ps[16], v[16];
    const int b = blockIdx.x, tid = threadIdx.x;

    float a4[4] = {0.f, 0.f, 0.f, 0.f};
    for (int p = 0; p < 8; ++p) {
        const float* pp = part + ((size_t)b * 8 + p) * 1024 + tid;
        a4[0] += pp[0]; a4[1] += pp[256]; a4[2] += pp[512]; a4[3] += pp[768];
    }
    #pragma unroll
    for (int q = 0; q < 4; ++q) {
        const int t = tid + q * 256;
        G[t >> 5][t & 31] = a4[q];
    }
    if (tid < 64) {
        float s = 0.f;
        for (int p = 0; p < 8; ++p) s += sums[((size_t)b * 8 + p) * 64 + tid];
        if (tid < 32) Sx[tid] = s; else Ss[tid - 32] = s;
    }
    __syncthreads();
    for (int t = tid; t < 512; t += 256) {
        const int c = t >> 5, f = t & 31;
        float s = 0.f;
        #pragma unroll
        for (int e = 0; e < 32; ++e) s = fmaf(wa[c * 32 + e], G[e][f], s);
        T[c][f] = s;
    }
    if (tid < 32) {
        const int c = tid & 15;
        const float* S = (tid < 16) ? Sx : Ss;
        float s = 0.f;
        #pragma unroll
        for (int e = 0; e < 32; ++e) s = fmaf(wa[c * 32 + e], S[e], s);
        if (tid < 16) px[c] = s; else ps[c] = s;
    }
    __syncthreads();
    {
        const int c = tid >> 4, d = tid & 15;
        float s = 0.f;
        #pragma unroll
        for (int f2 = 0; f2 < 32; ++f2) s = fmaf(T[c][f2], wa[d * 32 + f2], s);
        s += px[c] * ba[d] + ba[c] * ps[d] + 65536.f * ba[c] * ba[d];
        A[c][d] = s;
    }
    __syncthreads();
    if (tid < 16) {
        float m = A[tid][0];
        #pragma unroll
        for (int d = 1; d < 16; ++d) m = fmaxf(m, A[tid][d]);
        float s = 0.f;
        #pragma unroll
        for (int d = 0; d < 16; ++d) { const float e = expf(A[tid][d] - m); A[tid][d] = e; s += e; }
        const float inv = 1.f / s;
        #pragma unroll
        for (int d = 0; d < 16; ++d) A[tid][d] *= inv;
    }
    __syncthreads();
    if (tid < 16) {
        float s = wf[tid];
        #pragma unroll
        for (int c = 0; c < 16; ++c) s = fmaf(wf[c], A[c][tid], s);
        v[tid] = s;
    }
    __syncthreads();
    if (tid < 32) {
        float s = 0.f;
        #pragma unroll
        for (int d = 0; d < 16; ++d) s = fmaf(v[d], wa[d * 32 + tid], s);
        u[b * 32 + tid] = s;
    }
    if (tid == 0) {
        float s2 = bf[0];
        #pragma unroll
        for (int d = 0; d < 16; ++d) s2 = fmaf(v[d], ba[d], s2);
        cb[b] = s2;
    }
}

// ================= final: out[b][n] = sigmoid(cb + u . x3cl[b][n][:]) ==============
__launch_bounds__(256)
__global__ void final_k(const f16* __restrict__ x3, const float* __restrict__ u,
                        const float* __restrict__ cb, float* __restrict__ out) {
    const int b = blockIdx.y;
    const int nn = blockIdx.x * 256 + threadIdx.x;
    const f16* xb = x3 + ((size_t)b * 65536 + nn) * 32;
    const float* ub = u + b * 32;
    float acc = cb[b];
    #pragma unroll
    for (int g = 0; g < 4; ++g) {
        const h8 v = *(const h8*)(xb + g * 8);
        #pragma unroll
        for (int q = 0; q < 8; ++q) acc = fmaf(ub[g * 8 + q], (float)v[q], acc);
    }
    out[(size_t)b * 65536 + nn] = sigmoid_f(acc);
}

extern "C" void kernel_launch(void* const* d_in, const int* in_sizes, int n_in,
                              void* d_out, int out_size, void* d_ws, size_t ws_size,
                              hipStream_t stream) {
    const float* enc   = (const float*)d_in[0];
    const float* sem   = (const float*)d_in[1];
    const float* wt0   = (const float*)d_in[2];
    const float* bt0   = (const float*)d_in[3];
    const float* wc0   = (const float*)d_in[4];
    const float* bc0   = (const float*)d_in[5];
    const float* wt1   = (const float*)d_in[6];
    const float* bt1   = (const float*)d_in[7];
    const float* wc1   = (const float*)d_in[8];
    const float* bc1   = (const float*)d_in[9];
    const float* wt2   = (const float*)d_in[10];
    const float* bt2   = (const float*)d_in[11];
    const float* wc2   = (const float*)d_in[12];
    const float* bc2   = (const float*)d_in[13];
    const float* wt3   = (const float*)d_in[14];
    const float* bt3   = (const float*)d_in[15];
    const float* wc3   = (const float*)d_in[16];
    const float* bc3   = (const float*)d_in[17];
    const float* wattn = (const float*)d_in[18];
    const float* battn = (const float*)d_in[19];
    const float* wfin  = (const float*)d_in[20];
    const float* bfin  = (const float*)d_in[21];

    char* W = (char*)d_ws;
    f16*   actA   = (f16*)(W + 0);            // 32 MB
    f16*   actB   = (f16*)(W + 33554432);     // 32 MB
    f16*   x3cl   = (f16*)(W + 67108864);     // 32 MB: split-K partials early, x3 channel-LAST late
    float* pf     = (float*)(W + 67108864);   // alias (fp32 partials)
    f16*   wp     = (f16*)(W + 100663296);    // 4.7 MB
    f16*   enc_cl = (f16*)(W + 105906176);    // 2 MB
    float* part   = (float*)(W + 108003328);  // 4 MB
    float* sums   = (float*)(W + 112197632);  // 256 KB
    float* part2  = (float*)(W + 112459776);  // 256 KB
    float* sums2  = (float*)(W + 112721920);  // 16 KB
    float* u      = (float*)(W + 112738304);
    float* cb     = (float*)(W + 112739328);
    float* out    = (float*)d_out;

    P8 p;
    p.d[0] = {wt0, 0u,       256, 512, 1};
    p.d[1] = {wc0, 1179648u, 256, 256, 0};
    p.d[2] = {wt1, 1769472u, 128, 256, 1};
    p.d[3] = {wc1, 2064384u, 128, 128, 0};
    p.d[4] = {wt2, 2211840u,  64, 128, 1};
    p.d[5] = {wc2, 2285568u,  64,  64, 0};
    p.d[6] = {wt3, 2322432u,  32,  64, 1};
    p.d[7] = {wc3, 2340864u,  32,  32, 0};
    prep_weights_k<<<9180, 256, 0, stream>>>(p, wp);
    enc_transpose_k<<<128, 256, 0, stream>>>(enc, enc_cl);

    // L0: convT 512->256, 16x16 -> 32x32, split-K=4 (1024 blocks)
    convt_mfma<512, 256, 16, 16, 4><<<dim3(4, 4, 64), 256, 0, stream>>>(enc_cl, wp, nullptr, nullptr, pf);
    split_finish_k<4, 256><<<2048, 256, 0, stream>>>(pf, bt0, actA, 2097152);
    // L1: conv3 256ch, 32x32, split-K=4 (1024 blocks)
    conv3_mfma<256, 32, 32, 8, 32, 2, 4><<<dim3(4, 4, 64), 256, 0, stream>>>(actA, wp + 1179648, nullptr, nullptr, pf);
    split_finish_k<4, 256><<<2048, 256, 0, stream>>>(pf, bc0, actB, 2097152);
    // L2: convT 256->128, 32x32 -> 64x64, split-K=2 (1024 blocks)
    convt_mfma<256, 128, 32, 32, 2><<<dim3(4, 8, 32), 256, 0, stream>>>(actB, wp + 1769472, nullptr, nullptr, pf);
    split_finish_k<2, 128><<<4096, 256, 0, stream>>>(pf, bt1, actA, 4194304);
    // L3: conv3 128ch, 64x64, split-K=2 (1024 blocks)
    conv3_mfma<128, 64, 64, 4, 64, 4, 2><<<dim3(2, 16, 32), 256, 0, stream>>>(actA, wp + 2064384, nullptr, nullptr, pf);
    split_finish_k<2, 128><<<4096, 256, 0, stream>>>(pf, bc1, actB, 4194304);
    // L4-L7: direct
    convt_mfma<128, 64, 64, 64, 1>     <<<dim3(4, 16, 16), 256, 0, stream>>>(actB, wp + 2211840, bt2, actA, nullptr);
    conv3_mfma<64, 128, 128, 4, 64, 4, 1><<<dim3(2, 32, 16), 256, 0, stream>>>(actA, wp + 2285568, bc2, actB, nullptr);
    convt_mfma<64, 32, 128, 128, 1>    <<<dim3(8, 32, 8),  256, 0, stream>>>(actB, wp + 2322432, bt3, actA, nullptr);
    conv3_mfma<32, 256, 256, 4, 64, 4, 1><<<dim3(4, 64, 8), 256, 0, stream>>>(actA, wp + 2340864, bc3, x3cl, nullptr);

    gram_mfma_k<<<dim3(KCH, 8), 256, 0, stream>>>(x3cl, sem, part, sums);
    gram_reduce_k<<<dim3(8, 8), 256, 0, stream>>>(part, sums, part2, sums2);
    attn_finish_v3<<<8, 256, 0, stream>>>(part2, sums2, wattn, battn, wfin, bfin, u, cb);
    final_k<<<dim3(256, 8), 256, 0, stream>>>(x3cl, u, cb, out);
}